// Round 1
// baseline (805.344 us; speedup 1.0000x reference)
//
#include <hip/hip_runtime.h>
#include <hip/hip_bf16.h>
#include <cstdint>
#include <cstddef>

// Shapes (fixed by the problem): B=64, N=1024, D=512, S=16, 3 iterations.
// Workspace budget ~236 MB (x_bf16 67MB + kv 134MB + ~35MB small buffers).

typedef __bf16 bf16x8 __attribute__((ext_vector_type(8)));
typedef float f32x4 __attribute__((ext_vector_type(4)));

__device__ __forceinline__ float bf2f(unsigned short u) {
  union { unsigned int i; float f; } v; v.i = ((unsigned int)u) << 16; return v.f;
}
__device__ __forceinline__ unsigned short f2bf(float x) {
  __hip_bfloat16 h = __float2bfloat16(x);
  unsigned short u;
  __builtin_memcpy(&u, &h, 2);
  return u;
}

// ---------------- elementwise kernels ----------------

__global__ void cast_bf16_k(const float* __restrict__ in, unsigned short* __restrict__ out, int n) {
  int i = blockIdx.x * 256 + threadIdx.x;
  if (i < n) out[i] = f2bf(in[i]);
}

__global__ void init_slots_k(const float* __restrict__ mu, const float* __restrict__ ls,
                             const float* __restrict__ noise, float* __restrict__ slots) {
  int i = blockIdx.x * 256 + threadIdx.x;  // total 64*16*512 = 524288
  int d = i & 511;
  slots[i] = mu[d] + expf(ls[d]) * noise[i];
}

// GRU elementwise: gates ordered (r,z,n); gi/gh are [rows,1536], h/out [rows,512]
__global__ void gru_k(const float* __restrict__ gi, const float* __restrict__ gh,
                      const float* __restrict__ hp, float* __restrict__ ho) {
  int i = blockIdx.x * 256 + threadIdx.x;  // 524288
  int row = i >> 9, d = i & 511;
  size_t base = (size_t)row * 1536;
  float r = gi[base + d] + gh[base + d];
  r = 1.0f / (1.0f + expf(-r));
  float z = gi[base + 512 + d] + gh[base + 512 + d];
  z = 1.0f / (1.0f + expf(-z));
  float n = gi[base + 1024 + d] + r * gh[base + 1024 + d];
  n = tanhf(n);
  float h = hp[i];
  ho[i] = (1.0f - z) * n + z * h;
}

// ---------------- layernorm: one wave per row, D=512, bf16 out ----------------

__global__ __launch_bounds__(256) void ln_rows_k(
    const float* __restrict__ in, const float* __restrict__ g, const float* __restrict__ b,
    unsigned short* __restrict__ out, int rows) {
  int w = threadIdx.x >> 6, lane = threadIdx.x & 63;
  int row = (blockIdx.x << 2) + w;
  if (row >= rows) return;
  const float4* rp = reinterpret_cast<const float4*>(in + (size_t)row * 512);
  float4 v0 = rp[lane];
  float4 v1 = rp[lane + 64];
  float s = v0.x + v0.y + v0.z + v0.w + v1.x + v1.y + v1.z + v1.w;
  float q = v0.x*v0.x + v0.y*v0.y + v0.z*v0.z + v0.w*v0.w
          + v1.x*v1.x + v1.y*v1.y + v1.z*v1.z + v1.w*v1.w;
  #pragma unroll
  for (int o = 32; o > 0; o >>= 1) { s += __shfl_xor(s, o); q += __shfl_xor(q, o); }
  float m = s * (1.0f / 512.0f);
  float var = q * (1.0f / 512.0f) - m * m;
  float rstd = rsqrtf(var + 1e-8f);
  const float4* gp = reinterpret_cast<const float4*>(g);
  const float4* bp = reinterpret_cast<const float4*>(b);
  float4 g0 = gp[lane], g1 = gp[lane + 64];
  float4 b0 = bp[lane], b1 = bp[lane + 64];
  ushort4 o0, o1;
  o0.x = f2bf((v0.x - m) * rstd * g0.x + b0.x);
  o0.y = f2bf((v0.y - m) * rstd * g0.y + b0.y);
  o0.z = f2bf((v0.z - m) * rstd * g0.z + b0.z);
  o0.w = f2bf((v0.w - m) * rstd * g0.w + b0.w);
  o1.x = f2bf((v1.x - m) * rstd * g1.x + b1.x);
  o1.y = f2bf((v1.y - m) * rstd * g1.y + b1.y);
  o1.z = f2bf((v1.z - m) * rstd * g1.z + b1.z);
  o1.w = f2bf((v1.w - m) * rstd * g1.w + b1.w);
  ushort4* op = reinterpret_cast<ushort4*>(out + (size_t)row * 512);
  op[lane] = o0;
  op[lane + 64] = o1;
}

// ---------------- MFMA GEMM: C[M,N] = A[M,K] @ W[N,K]^T (+bias)(+addsrc)(relu) ----------------
// A, W bf16 row-major K-contiguous. 128x128 tile, BK=32, 4 waves of 64x64.
// Requires M%128==0, N%128==0, K%32==0.

#define LPAD 56  // row stride 112B: 16B-aligned, only 2-way bank aliasing (free)

template<int BIAS, int RELU, int ADDSRC, int OUTBF16>
__global__ __launch_bounds__(256) void gemm_bt(
    const unsigned short* __restrict__ A, const unsigned short* __restrict__ W,
    const float* __restrict__ bias, const float* __restrict__ addsrc,
    void* __restrict__ Cout, int M, int N, int K) {
  __shared__ unsigned short sA[128][LPAD];
  __shared__ unsigned short sB[128][LPAD];
  const int row0 = blockIdx.y << 7, col0 = blockIdx.x << 7;
  const int tid = threadIdx.x;
  const int lane = tid & 63, wid = tid >> 6;
  const int wm = (wid >> 1) << 6, wn = (wid & 1) << 6;
  const int lrow = lane & 15, kt = (lane >> 4) << 3;
  const int sr = tid >> 2, sc = (tid & 3) << 3;  // staging: thread -> 2 rows x 8 elems

  f32x4 acc[4][4];
  #pragma unroll
  for (int m = 0; m < 4; ++m)
    #pragma unroll
    for (int n = 0; n < 4; ++n)
      acc[m][n] = f32x4{0.f, 0.f, 0.f, 0.f};

  for (int k0 = 0; k0 < K; k0 += 32) {
    #pragma unroll
    for (int i = 0; i < 2; ++i) {
      int r = sr + (i << 6);
      *reinterpret_cast<uint4*>(&sA[r][sc]) =
          *reinterpret_cast<const uint4*>(A + (size_t)(row0 + r) * K + k0 + sc);
      *reinterpret_cast<uint4*>(&sB[r][sc]) =
          *reinterpret_cast<const uint4*>(W + (size_t)(col0 + r) * K + k0 + sc);
    }
    __syncthreads();
    bf16x8 af[4], bfv[4];
    #pragma unroll
    for (int m = 0; m < 4; ++m)
      af[m] = *reinterpret_cast<const bf16x8*>(&sA[wm + m * 16 + lrow][kt]);
    #pragma unroll
    for (int n = 0; n < 4; ++n)
      bfv[n] = *reinterpret_cast<const bf16x8*>(&sB[wn + n * 16 + lrow][kt]);
    #pragma unroll
    for (int m = 0; m < 4; ++m)
      #pragma unroll
      for (int n = 0; n < 4; ++n)
        acc[m][n] = __builtin_amdgcn_mfma_f32_16x16x32_bf16(af[m], bfv[n], acc[m][n], 0, 0, 0);
    __syncthreads();
  }

  const int rb = (lane >> 4) << 2;  // C/D: col = lane&15, row = (lane>>4)*4 + reg
  #pragma unroll
  for (int m = 0; m < 4; ++m) {
    #pragma unroll
    for (int n = 0; n < 4; ++n) {
      int col = col0 + wn + n * 16 + lrow;
      float bv = BIAS ? bias[col] : 0.0f;
      #pragma unroll
      for (int r = 0; r < 4; ++r) {
        int row = row0 + wm + m * 16 + rb + r;
        float v = acc[m][n][r] + bv;
        if (ADDSRC) v += addsrc[(size_t)row * N + col];
        if (RELU) v = fmaxf(v, 0.0f);
        if (OUTBF16) ((unsigned short*)Cout)[(size_t)row * N + col] = f2bf(v);
        else ((float*)Cout)[(size_t)row * N + col] = v;
      }
    }
  }
}

// ---------------- attention: logits[b,s,n] = scale * q[b,s,:]·k[b,n,:] ----------------
// grid (N/64, B), block 256. Wave w handles s-group w (4 slots), lanes = 64 n values.

__global__ __launch_bounds__(256) void logits_k(
    const unsigned short* __restrict__ q, const unsigned short* __restrict__ kv,
    float* __restrict__ out) {
  __shared__ float sq[16][512];
  int b = blockIdx.y, nc = blockIdx.x;
  for (int i = threadIdx.x; i < 8192; i += 256)
    sq[i >> 9][i & 511] = bf2f(q[((size_t)b << 13) + i]);
  __syncthreads();
  int nl = threadIdx.x & 63, sg = threadIdx.x >> 6;
  int n = (nc << 6) + nl;
  const unsigned short* kr = kv + (((size_t)b << 10) + n) * 1024;  // cols [0,512) = k
  const float* s0 = sq[sg * 4 + 0];
  const float* s1 = sq[sg * 4 + 1];
  const float* s2 = sq[sg * 4 + 2];
  const float* s3 = sq[sg * 4 + 3];
  float a0 = 0.f, a1 = 0.f, a2 = 0.f, a3 = 0.f;
  for (int k0 = 0; k0 < 512; k0 += 8) {
    uint4 u = *reinterpret_cast<const uint4*>(kr + k0);
    float kf[8];
    kf[0] = bf2f(u.x & 0xffff); kf[1] = bf2f(u.x >> 16);
    kf[2] = bf2f(u.y & 0xffff); kf[3] = bf2f(u.y >> 16);
    kf[4] = bf2f(u.z & 0xffff); kf[5] = bf2f(u.z >> 16);
    kf[6] = bf2f(u.w & 0xffff); kf[7] = bf2f(u.w >> 16);
    #pragma unroll
    for (int e = 0; e < 8; ++e) {
      a0 += kf[e] * s0[k0 + e];
      a1 += kf[e] * s1[k0 + e];
      a2 += kf[e] * s2[k0 + e];
      a3 += kf[e] * s3[k0 + e];
    }
  }
  const float scale = 0.044194173824159216f;  // 512^-0.5
  float* ob = out + ((size_t)b << 14) + ((size_t)(sg * 4)) * 1024 + n;
  ob[0] = a0 * scale; ob[1024] = a1 * scale; ob[2048] = a2 * scale; ob[3072] = a3 * scale;
}

// ---------------- softmax over n (rows) then column-normalize over s ----------------
// one block per batch, 1024 threads (16 waves = 16 slot-rows)

__global__ __launch_bounds__(1024) void softmax_cn_k(
    const float* __restrict__ logits, unsigned short* __restrict__ attn) {
  __shared__ float sp[16][1024];
  int b = blockIdx.x;
  int w = threadIdx.x >> 6, lane = threadIdx.x & 63;
  const float* rp = logits + ((size_t)b * 16 + w) * 1024;
  float v[16];
  float mx = -3.4e38f;
  #pragma unroll
  for (int i = 0; i < 16; ++i) { v[i] = rp[lane + (i << 6)]; mx = fmaxf(mx, v[i]); }
  #pragma unroll
  for (int o = 32; o > 0; o >>= 1) mx = fmaxf(mx, __shfl_xor(mx, o));
  float s = 0.f;
  #pragma unroll
  for (int i = 0; i < 16; ++i) { v[i] = __expf(v[i] - mx); s += v[i]; }
  #pragma unroll
  for (int o = 32; o > 0; o >>= 1) s += __shfl_xor(s, o);
  float inv = 1.0f / s;
  #pragma unroll
  for (int i = 0; i < 16; ++i) sp[w][lane + (i << 6)] = v[i] * inv;
  __syncthreads();
  int col = threadIdx.x;
  float cs = 0.f;
  #pragma unroll
  for (int s2 = 0; s2 < 16; ++s2) cs += sp[s2][col];
  float rinv = 1.0f / (cs + 1e-8f);
  unsigned short* ob = attn + ((size_t)b << 14);
  #pragma unroll
  for (int s2 = 0; s2 < 16; ++s2) ob[s2 * 1024 + col] = f2bf(sp[s2][col] * rinv);
}

// ---------------- updates[b,s,d] = sum_n attn[b,s,n] * v[b,n,d] ----------------
// grid (4, B): d-chunk of 128; block 256: 128 d-lanes x 2 slot-halves

__global__ __launch_bounds__(256) void updates_k(
    const unsigned short* __restrict__ attn, const unsigned short* __restrict__ kv,
    unsigned short* __restrict__ upd) {
  __shared__ float sa[16][1024];
  int b = blockIdx.y, dc = blockIdx.x;
  for (int i = threadIdx.x; i < 16384; i += 256)
    sa[i >> 10][i & 1023] = bf2f(attn[((size_t)b << 14) + i]);
  __syncthreads();
  int d = (dc << 7) + (threadIdx.x & 127);
  int sh = threadIdx.x >> 7;
  float acc[8] = {0.f, 0.f, 0.f, 0.f, 0.f, 0.f, 0.f, 0.f};
  const unsigned short* vb = kv + ((size_t)b << 20) + 512 + d;  // b*1024*1024
  const float* sab = sa[sh * 8];
  for (int n = 0; n < 1024; ++n) {
    float vv = bf2f(vb[(size_t)n << 10]);
    #pragma unroll
    for (int j = 0; j < 8; ++j) acc[j] += sab[j * 1024 + n] * vv;
  }
  #pragma unroll
  for (int j = 0; j < 8; ++j)
    upd[((size_t)b * 16 + sh * 8 + j) * 512 + d] = f2bf(acc[j]);
}

// ---------------- host launch ----------------

extern "C" void kernel_launch(void* const* d_in, const int* in_sizes, int n_in,
                              void* d_out, int out_size, void* d_ws, size_t ws_size,
                              hipStream_t stream) {
  const float* inputs  = (const float*)d_in[0];
  const float* noise   = (const float*)d_in[1];
  const float* slot_mu = (const float*)d_in[2];
  const float* slot_ls = (const float*)d_in[3];
  const float* ln_in_g = (const float*)d_in[4];
  const float* ln_in_b = (const float*)d_in[5];
  const float* ln_s_g  = (const float*)d_in[6];
  const float* ln_s_b  = (const float*)d_in[7];
  const float* ln_m_g  = (const float*)d_in[8];
  const float* ln_m_b  = (const float*)d_in[9];
  const float* Wq   = (const float*)d_in[10];
  const float* Wk   = (const float*)d_in[11];
  const float* Wv   = (const float*)d_in[12];
  const float* w_ih = (const float*)d_in[13];
  const float* w_hh = (const float*)d_in[14];
  const float* b_ih = (const float*)d_in[15];
  const float* b_hh = (const float*)d_in[16];
  const float* w1   = (const float*)d_in[17];
  const float* b1   = (const float*)d_in[18];
  const float* w2   = (const float*)d_in[19];
  const float* b2   = (const float*)d_in[20];

  const int BN = 65536;   // B*N rows
  const int BS = 1024;    // B*S rows
  const int D = 512;

  uintptr_t base = (uintptr_t)d_ws;
  auto alloc = [&](size_t bytes) {
    void* p = (void*)base;
    base += (bytes + 255) & ~(size_t)255;
    return p;
  };
  unsigned short* x_bf    = (unsigned short*)alloc((size_t)BN * D * 2);
  unsigned short* kv_bf   = (unsigned short*)alloc((size_t)BN * 1024 * 2);
  unsigned short* wkv_bf  = (unsigned short*)alloc(1024 * 512 * 2);
  unsigned short* wq_bf   = (unsigned short*)alloc(512 * 512 * 2);
  unsigned short* wih_bf  = (unsigned short*)alloc(1536 * 512 * 2);
  unsigned short* whh_bf  = (unsigned short*)alloc(1536 * 512 * 2);
  unsigned short* w1_bf   = (unsigned short*)alloc(512 * 512 * 2);
  unsigned short* w2_bf   = (unsigned short*)alloc(512 * 512 * 2);
  float*          slots   = (float*)alloc((size_t)BS * D * 4);
  unsigned short* slots_bf= (unsigned short*)alloc((size_t)BS * D * 2);
  unsigned short* sn_bf   = (unsigned short*)alloc((size_t)BS * D * 2);
  unsigned short* q_bf    = (unsigned short*)alloc((size_t)BS * D * 2);
  float*          logits  = (float*)alloc((size_t)64 * 16 * 1024 * 4);
  unsigned short* attn_bf = (unsigned short*)alloc((size_t)64 * 16 * 1024 * 2);
  unsigned short* upd_bf  = (unsigned short*)alloc((size_t)BS * D * 2);
  float*          gi      = (float*)alloc((size_t)BS * 1536 * 4);
  float*          gh      = (float*)alloc((size_t)BS * 1536 * 4);
  float*          sgru    = (float*)alloc((size_t)BS * D * 4);
  unsigned short* lnm_bf  = (unsigned short*)alloc((size_t)BS * D * 2);
  unsigned short* h_bf    = (unsigned short*)alloc((size_t)BS * D * 2);
  (void)ws_size; (void)n_in; (void)in_sizes; (void)out_size;

  // --- weight casts (f32 -> bf16) ---
  cast_bf16_k<<<1024, 256, 0, stream>>>(Wk, wkv_bf, 262144);
  cast_bf16_k<<<1024, 256, 0, stream>>>(Wv, wkv_bf + 262144, 262144);
  cast_bf16_k<<<1024, 256, 0, stream>>>(Wq, wq_bf, 262144);
  cast_bf16_k<<<3072, 256, 0, stream>>>(w_ih, wih_bf, 786432);
  cast_bf16_k<<<3072, 256, 0, stream>>>(w_hh, whh_bf, 786432);
  cast_bf16_k<<<1024, 256, 0, stream>>>(w1, w1_bf, 262144);
  cast_bf16_k<<<1024, 256, 0, stream>>>(w2, w2_bf, 262144);

  // --- slots init, LN(inputs), fused k|v projection ---
  init_slots_k<<<2048, 256, 0, stream>>>(slot_mu, slot_ls, noise, slots);
  ln_rows_k<<<16384, 256, 0, stream>>>(inputs, ln_in_g, ln_in_b, x_bf, BN);
  gemm_bt<0,0,0,1><<<dim3(8, 512), 256, 0, stream>>>(
      x_bf, wkv_bf, nullptr, nullptr, kv_bf, BN, 1024, 512);

  for (int it = 0; it < 3; ++it) {
    cast_bf16_k<<<2048, 256, 0, stream>>>(slots, slots_bf, BS * D);
    ln_rows_k<<<256, 256, 0, stream>>>(slots, ln_s_g, ln_s_b, sn_bf, BS);
    gemm_bt<0,0,0,1><<<dim3(4, 8), 256, 0, stream>>>(
        sn_bf, wq_bf, nullptr, nullptr, q_bf, BS, 512, 512);
    logits_k<<<dim3(16, 64), 256, 0, stream>>>(q_bf, kv_bf, logits);
    softmax_cn_k<<<64, 1024, 0, stream>>>(logits, attn_bf);
    updates_k<<<dim3(4, 64), 256, 0, stream>>>(attn_bf, kv_bf, upd_bf);
    gemm_bt<1,0,0,0><<<dim3(12, 8), 256, 0, stream>>>(
        upd_bf, wih_bf, b_ih, nullptr, gi, BS, 1536, 512);
    gemm_bt<1,0,0,0><<<dim3(12, 8), 256, 0, stream>>>(
        slots_bf, whh_bf, b_hh, nullptr, gh, BS, 1536, 512);
    gru_k<<<2048, 256, 0, stream>>>(gi, gh, slots, sgru);
    ln_rows_k<<<256, 256, 0, stream>>>(sgru, ln_m_g, ln_m_b, lnm_bf, BS);
    gemm_bt<1,1,0,1><<<dim3(4, 8), 256, 0, stream>>>(
        lnm_bf, w1_bf, b1, nullptr, h_bf, BS, 512, 512);
    float* slots_out = (it == 2) ? (float*)d_out : slots;
    gemm_bt<1,0,1,0><<<dim3(4, 8), 256, 0, stream>>>(
        h_bf, w2_bf, b2, sgru, slots_out, BS, 512, 512);
  }
}

// Round 3
// 792.478 us; speedup vs baseline: 1.0162x; 1.0162x over previous
//
#include <hip/hip_runtime.h>
#include <hip/hip_bf16.h>
#include <cstdint>
#include <cstddef>

// Shapes fixed: B=64, N=1024, D=512, S=16, 3 iterations.

typedef __bf16 bf16x8 __attribute__((ext_vector_type(8)));
typedef float f32x4 __attribute__((ext_vector_type(4)));

__device__ __forceinline__ float bf2f(unsigned int u) {
  union { unsigned int i; float f; } v; v.i = u << 16; return v.f;
}
__device__ __forceinline__ unsigned short f2bf(float x) {
  __hip_bfloat16 h = __float2bfloat16(x);
  unsigned short u;
  __builtin_memcpy(&u, &h, 2);
  return u;
}

#define GLD16(gp, lp)                                                       \
  __builtin_amdgcn_global_load_lds(                                         \
      (const __attribute__((address_space(1))) void*)(gp),                  \
      (__attribute__((address_space(3))) void*)(lp), 16, 0, 0)

// ---------------- elementwise ----------------

__global__ void cast_bf16_k(const float* __restrict__ in, unsigned short* __restrict__ out, int n) {
  int i = blockIdx.x * 256 + threadIdx.x;
  if (i < n) out[i] = f2bf(in[i]);
}

__global__ void init_slots_k(const float* __restrict__ mu, const float* __restrict__ ls,
                             const float* __restrict__ noise, float* __restrict__ slots) {
  int i = blockIdx.x * 256 + threadIdx.x;
  int d = i & 511;
  slots[i] = mu[d] + expf(ls[d]) * noise[i];
}

// W'[e,k] = sum_d Wq[d,e] * Wk[d,k]  -> bf16 rows [0,512) of the kv weight
__global__ __launch_bounds__(256) void wcomp_k(const float* __restrict__ Wq,
                                               const float* __restrict__ Wk,
                                               unsigned short* __restrict__ Wout) {
  int kp = (blockIdx.x << 8) + threadIdx.x;  // grid.x = 2
  int e0 = blockIdx.y << 3;                  // grid.y = 64
  float acc[8] = {0.f, 0.f, 0.f, 0.f, 0.f, 0.f, 0.f, 0.f};
  for (int d = 0; d < 512; ++d) {
    float wk = Wk[d * 512 + kp];
    #pragma unroll
    for (int j = 0; j < 8; ++j) acc[j] += Wq[d * 512 + e0 + j] * wk;
  }
  #pragma unroll
  for (int j = 0; j < 8; ++j) Wout[(size_t)(e0 + j) * 512 + kp] = f2bf(acc[j]);
}

// ---------------- layernorm (wave per row, D=512) ----------------

__global__ __launch_bounds__(256) void ln_rows_k(
    const float* __restrict__ in, const float* __restrict__ g, const float* __restrict__ b,
    unsigned short* __restrict__ out, int rows) {
  int w = threadIdx.x >> 6, lane = threadIdx.x & 63;
  int row = (blockIdx.x << 2) + w;
  if (row >= rows) return;
  const float4* rp = reinterpret_cast<const float4*>(in + (size_t)row * 512);
  float4 v0 = rp[lane], v1 = rp[lane + 64];
  float s = v0.x + v0.y + v0.z + v0.w + v1.x + v1.y + v1.z + v1.w;
  float q = v0.x*v0.x + v0.y*v0.y + v0.z*v0.z + v0.w*v0.w
          + v1.x*v1.x + v1.y*v1.y + v1.z*v1.z + v1.w*v1.w;
  #pragma unroll
  for (int o = 32; o > 0; o >>= 1) { s += __shfl_xor(s, o); q += __shfl_xor(q, o); }
  float m = s * (1.0f / 512.0f);
  float rstd = rsqrtf(q * (1.0f / 512.0f) - m * m + 1e-8f);
  const float4* gp = reinterpret_cast<const float4*>(g);
  const float4* bp = reinterpret_cast<const float4*>(b);
  float4 g0 = gp[lane], g1 = gp[lane + 64];
  float4 b0 = bp[lane], b1 = bp[lane + 64];
  ushort4 o0, o1;
  o0.x = f2bf((v0.x - m) * rstd * g0.x + b0.x);
  o0.y = f2bf((v0.y - m) * rstd * g0.y + b0.y);
  o0.z = f2bf((v0.z - m) * rstd * g0.z + b0.z);
  o0.w = f2bf((v0.w - m) * rstd * g0.w + b0.w);
  o1.x = f2bf((v1.x - m) * rstd * g1.x + b1.x);
  o1.y = f2bf((v1.y - m) * rstd * g1.y + b1.y);
  o1.z = f2bf((v1.z - m) * rstd * g1.z + b1.z);
  o1.w = f2bf((v1.w - m) * rstd * g1.w + b1.w);
  ushort4* op = reinterpret_cast<ushort4*>(out + (size_t)row * 512);
  op[lane] = o0; op[lane + 64] = o1;
}

// LN(slots)->sn_bf AND raw cast slots->slots_bf, one pass
__global__ __launch_bounds__(256) void ln_cast_k(
    const float* __restrict__ in, const float* __restrict__ g, const float* __restrict__ b,
    unsigned short* __restrict__ sn, unsigned short* __restrict__ raw) {
  int w = threadIdx.x >> 6, lane = threadIdx.x & 63;
  int row = (blockIdx.x << 2) + w;
  const float4* rp = reinterpret_cast<const float4*>(in + (size_t)row * 512);
  float4 v0 = rp[lane], v1 = rp[lane + 64];
  float s = v0.x + v0.y + v0.z + v0.w + v1.x + v1.y + v1.z + v1.w;
  float q = v0.x*v0.x + v0.y*v0.y + v0.z*v0.z + v0.w*v0.w
          + v1.x*v1.x + v1.y*v1.y + v1.z*v1.z + v1.w*v1.w;
  #pragma unroll
  for (int o = 32; o > 0; o >>= 1) { s += __shfl_xor(s, o); q += __shfl_xor(q, o); }
  float m = s * (1.0f / 512.0f);
  float rstd = rsqrtf(q * (1.0f / 512.0f) - m * m + 1e-8f);
  const float4* gp = reinterpret_cast<const float4*>(g);
  const float4* bp = reinterpret_cast<const float4*>(b);
  float4 g0 = gp[lane], g1 = gp[lane + 64];
  float4 b0 = bp[lane], b1 = bp[lane + 64];
  ushort4 c0, c1, o0, o1;
  c0.x = f2bf(v0.x); c0.y = f2bf(v0.y); c0.z = f2bf(v0.z); c0.w = f2bf(v0.w);
  c1.x = f2bf(v1.x); c1.y = f2bf(v1.y); c1.z = f2bf(v1.z); c1.w = f2bf(v1.w);
  o0.x = f2bf((v0.x - m) * rstd * g0.x + b0.x);
  o0.y = f2bf((v0.y - m) * rstd * g0.y + b0.y);
  o0.z = f2bf((v0.z - m) * rstd * g0.z + b0.z);
  o0.w = f2bf((v0.w - m) * rstd * g0.w + b0.w);
  o1.x = f2bf((v1.x - m) * rstd * g1.x + b1.x);
  o1.y = f2bf((v1.y - m) * rstd * g1.y + b1.y);
  o1.z = f2bf((v1.z - m) * rstd * g1.z + b1.z);
  o1.w = f2bf((v1.w - m) * rstd * g1.w + b1.w);
  ushort4* sp_ = reinterpret_cast<ushort4*>(sn + (size_t)row * 512);
  ushort4* cp_ = reinterpret_cast<ushort4*>(raw + (size_t)row * 512);
  sp_[lane] = o0; sp_[lane + 64] = o1;
  cp_[lane] = c0; cp_[lane + 64] = c1;
}

// GRU elementwise + LN fused: wave per row. sgru = gru output (f32), lnm = LN(sgru) bf16
__global__ __launch_bounds__(256) void gru_ln_k(
    const float* __restrict__ gi, const float* __restrict__ gh, const float* __restrict__ hp,
    const float* __restrict__ g, const float* __restrict__ b,
    float* __restrict__ sgru, unsigned short* __restrict__ lnm) {
  int w = threadIdx.x >> 6, lane = threadIdx.x & 63;
  int row = (blockIdx.x << 2) + w;
  size_t gb = (size_t)row * 1536 + (lane << 3);
  size_t hb = (size_t)row * 512 + (lane << 3);
  float ir[8], iz[8], in_[8], hr[8], hz[8], hn[8], hv[8], y[8];
  #pragma unroll
  for (int c = 0; c < 2; ++c) {
    *reinterpret_cast<float4*>(ir + 4*c)  = *reinterpret_cast<const float4*>(gi + gb + 4*c);
    *reinterpret_cast<float4*>(iz + 4*c)  = *reinterpret_cast<const float4*>(gi + gb + 512 + 4*c);
    *reinterpret_cast<float4*>(in_ + 4*c) = *reinterpret_cast<const float4*>(gi + gb + 1024 + 4*c);
    *reinterpret_cast<float4*>(hr + 4*c)  = *reinterpret_cast<const float4*>(gh + gb + 4*c);
    *reinterpret_cast<float4*>(hz + 4*c)  = *reinterpret_cast<const float4*>(gh + gb + 512 + 4*c);
    *reinterpret_cast<float4*>(hn + 4*c)  = *reinterpret_cast<const float4*>(gh + gb + 1024 + 4*c);
    *reinterpret_cast<float4*>(hv + 4*c)  = *reinterpret_cast<const float4*>(hp + hb + 4*c);
  }
  float s = 0.f, q = 0.f;
  #pragma unroll
  for (int j = 0; j < 8; ++j) {
    float r = 1.0f / (1.0f + expf(-(ir[j] + hr[j])));
    float z = 1.0f / (1.0f + expf(-(iz[j] + hz[j])));
    float n = tanhf(in_[j] + r * hn[j]);
    float h = (1.0f - z) * n + z * hv[j];
    y[j] = h; s += h; q += h * h;
  }
  #pragma unroll
  for (int o = 32; o > 0; o >>= 1) { s += __shfl_xor(s, o); q += __shfl_xor(q, o); }
  float m = s * (1.0f / 512.0f);
  float rstd = rsqrtf(q * (1.0f / 512.0f) - m * m + 1e-8f);
  const float* gg = g + (lane << 3);
  const float* bb = b + (lane << 3);
  #pragma unroll
  for (int c = 0; c < 2; ++c)
    *reinterpret_cast<float4*>(sgru + hb + 4*c) = *reinterpret_cast<const float4*>(y + 4*c);
  uint4 o4;
  unsigned int p[8];
  #pragma unroll
  for (int j = 0; j < 8; ++j) p[j] = f2bf((y[j] - m) * rstd * gg[j] + bb[j]);
  o4.x = p[0] | (p[1] << 16); o4.y = p[2] | (p[3] << 16);
  o4.z = p[4] | (p[5] << 16); o4.w = p[6] | (p[7] << 16);
  *reinterpret_cast<uint4*>(lnm + hb) = o4;
}

// ---------------- MFMA GEMM: C[M,N] = A[M,K] @ W[N,K]^T, gload_lds + 2-buffer pipeline ----------------
// M%128==0, N%128==0, K%32==0. 128x128 tile, BK=32, 4 waves of 64x64.
// Staging: 8 GLD16 instrs per operand per K-step; instr ii covers tile rows
// [ii*16, ii*16+16) -> LDS shorts offset ii*512 (lane l -> +8*l shorts).

template<int BIAS, int RELU, int ADDSRC, int OUTBF16>
__global__ __launch_bounds__(256) void gemm_bt(
    const unsigned short* __restrict__ A, const unsigned short* __restrict__ W,
    const float* __restrict__ bias, const float* __restrict__ addsrc,
    void* __restrict__ Cout, int M, int N, int K) {
  __shared__ unsigned short sA[2][4096];  // [128][32] linear
  __shared__ unsigned short sB[2][4096];
  const int tid = threadIdx.x;
  const int lane = tid & 63, w = tid >> 6;

  // XCD-aware bijective swizzle (all grids here have nwg % 8 == 0)
  int nwg = gridDim.x * gridDim.y;
  int flat = blockIdx.y * gridDim.x + blockIdx.x;
  if ((nwg & 7) == 0) { int c = nwg >> 3; flat = (flat & 7) * c + (flat >> 3); }
  const int row0 = (flat / gridDim.x) << 7;
  const int col0 = (flat % gridDim.x) << 7;

  const int wm = (w >> 1) << 6, wn = (w & 1) << 6;
  const int lrow = lane & 15, kt = (lane >> 4) << 3;
  const int srow = lane >> 2, scol = (lane & 3) << 3;

  f32x4 acc[4][4];
  #pragma unroll
  for (int m = 0; m < 4; ++m)
    #pragma unroll
    for (int n = 0; n < 4; ++n) acc[m][n] = f32x4{0.f, 0.f, 0.f, 0.f};

  auto stage = [&](int buf, int k0) {
    #pragma unroll
    for (int i = 0; i < 2; ++i) {
      int ii = w * 2 + i;
      int r = (ii << 4) + srow;
      GLD16(A + (size_t)(row0 + r) * K + k0 + scol, &sA[buf][ii * 512]);
      GLD16(W + (size_t)(col0 + r) * K + k0 + scol, &sB[buf][ii * 512]);
    }
  };

  stage(0, 0);
  const int nt = K >> 5;
  int cur = 0;
  for (int t = 0; t < nt; ++t) {
    __syncthreads();                      // drains vmcnt(0) -> buf[cur] ready
    if (t + 1 < nt) stage(cur ^ 1, (t + 1) << 5);
    bf16x8 af[4], bfv[4];
    #pragma unroll
    for (int m = 0; m < 4; ++m)
      af[m] = *reinterpret_cast<const bf16x8*>(&sA[cur][(wm + m * 16 + lrow) * 32 + kt]);
    #pragma unroll
    for (int n = 0; n < 4; ++n)
      bfv[n] = *reinterpret_cast<const bf16x8*>(&sB[cur][(wn + n * 16 + lrow) * 32 + kt]);
    #pragma unroll
    for (int m = 0; m < 4; ++m)
      #pragma unroll
      for (int n = 0; n < 4; ++n)
        acc[m][n] = __builtin_amdgcn_mfma_f32_16x16x32_bf16(af[m], bfv[n], acc[m][n], 0, 0, 0);
    cur ^= 1;
  }

  const int rb = (lane >> 4) << 2;  // C/D: col = lane&15, row = (lane>>4)*4 + reg
  #pragma unroll
  for (int m = 0; m < 4; ++m) {
    #pragma unroll
    for (int n = 0; n < 4; ++n) {
      int col = col0 + wn + n * 16 + lrow;
      float bv = BIAS ? bias[col] : 0.0f;
      #pragma unroll
      for (int r = 0; r < 4; ++r) {
        int row = row0 + wm + m * 16 + rb + r;
        float v = acc[m][n][r] + bv;
        if (ADDSRC) v += addsrc[(size_t)row * N + col];
        if (RELU) v = fmaxf(v, 0.0f);
        if (OUTBF16) ((unsigned short*)Cout)[(size_t)row * N + col] = f2bf(v);
        else ((float*)Cout)[(size_t)row * N + col] = v;
      }
    }
  }
}

// ---------------- logits[b,s,n] = scale * sn[b,s,:]·k2[b,n,:] ----------------

__global__ __launch_bounds__(256) void logits_k(
    const unsigned short* __restrict__ sn, const unsigned short* __restrict__ kv,
    float* __restrict__ out) {
  __shared__ float sq[16][512];
  int b = blockIdx.y, nc = blockIdx.x;
  for (int i = threadIdx.x; i < 8192; i += 256)
    sq[i >> 9][i & 511] = bf2f(sn[((size_t)b << 13) + i]);
  __syncthreads();
  int nl = threadIdx.x & 63, sg = threadIdx.x >> 6;
  int n = (nc << 6) + nl;
  const unsigned short* kr = kv + (((size_t)b << 10) + n) * 1024;  // cols [0,512) = k2
  const float* s0 = sq[sg * 4 + 0];
  const float* s1 = sq[sg * 4 + 1];
  const float* s2 = sq[sg * 4 + 2];
  const float* s3 = sq[sg * 4 + 3];
  float a0 = 0.f, a1 = 0.f, a2 = 0.f, a3 = 0.f;
  for (int k0 = 0; k0 < 512; k0 += 8) {
    uint4 u = *reinterpret_cast<const uint4*>(kr + k0);
    float kf[8];
    kf[0] = bf2f(u.x & 0xffff); kf[1] = bf2f(u.x >> 16);
    kf[2] = bf2f(u.y & 0xffff); kf[3] = bf2f(u.y >> 16);
    kf[4] = bf2f(u.z & 0xffff); kf[5] = bf2f(u.z >> 16);
    kf[6] = bf2f(u.w & 0xffff); kf[7] = bf2f(u.w >> 16);
    #pragma unroll
    for (int e = 0; e < 8; ++e) {
      a0 += kf[e] * s0[k0 + e];
      a1 += kf[e] * s1[k0 + e];
      a2 += kf[e] * s2[k0 + e];
      a3 += kf[e] * s3[k0 + e];
    }
  }
  const float scale = 0.044194173824159216f;  // 512^-0.5
  float* ob = out + ((size_t)b << 14) + ((size_t)(sg * 4)) * 1024 + n;
  ob[0] = a0 * scale; ob[1024] = a1 * scale; ob[2048] = a2 * scale; ob[3072] = a3 * scale;
}

// ---------------- softmax over n, column-normalize over s; f32 attn out ----------------

__global__ __launch_bounds__(1024) void softmax_cn_k(
    const float* __restrict__ logits, float* __restrict__ attn) {
  __shared__ float sp[16][1024];
  int b = blockIdx.x;
  int w = threadIdx.x >> 6, lane = threadIdx.x & 63;
  const float* rp = logits + ((size_t)b * 16 + w) * 1024;
  float v[16];
  float mx = -3.4e38f;
  #pragma unroll
  for (int i = 0; i < 16; ++i) { v[i] = rp[lane + (i << 6)]; mx = fmaxf(mx, v[i]); }
  #pragma unroll
  for (int o = 32; o > 0; o >>= 1) mx = fmaxf(mx, __shfl_xor(mx, o));
  float s = 0.f;
  #pragma unroll
  for (int i = 0; i < 16; ++i) { v[i] = __expf(v[i] - mx); s += v[i]; }
  #pragma unroll
  for (int o = 32; o > 0; o >>= 1) s += __shfl_xor(s, o);
  float inv = 1.0f / s;
  #pragma unroll
  for (int i = 0; i < 16; ++i) sp[w][lane + (i << 6)] = v[i] * inv;
  __syncthreads();
  int col = threadIdx.x;
  float cs = 0.f;
  #pragma unroll
  for (int s2 = 0; s2 < 16; ++s2) cs += sp[s2][col];
  float rinv = 1.0f / (cs + 1e-8f);
  float* ob = attn + ((size_t)b << 14);
  #pragma unroll
  for (int s2 = 0; s2 < 16; ++s2) ob[s2 * 1024 + col] = sp[s2][col] * rinv;
}

// ---------------- updates[b,s,d] = sum_n attn[b,s,n] * v[b,n,d] ----------------
// grid (4, B); block 256 = 16 d-lanes (8 elems each, uint4 v loads) x 16 slots

__global__ __launch_bounds__(256) void updates_k(
    const float* __restrict__ attn, const unsigned short* __restrict__ kv,
    unsigned short* __restrict__ upd) {
  __shared__ float sa[16][1024];
  int b = blockIdx.y, dc = blockIdx.x;
  for (int i = threadIdx.x; i < 16384; i += 256)
    sa[i >> 10][i & 1023] = attn[((size_t)b << 14) + i];
  __syncthreads();
  int l16 = threadIdx.x & 15, slot = threadIdx.x >> 4;
  int d = (dc << 7) + (l16 << 3);
  const unsigned short* vb = kv + ((size_t)b << 20) + 512 + d;
  const float* sr = sa[slot];
  float acc[8] = {0.f, 0.f, 0.f, 0.f, 0.f, 0.f, 0.f, 0.f};
  for (int n = 0; n < 1024; ++n) {
    uint4 u = *reinterpret_cast<const uint4*>(vb + ((size_t)n << 10));
    float a = sr[n];
    acc[0] += a * bf2f(u.x & 0xffff); acc[1] += a * bf2f(u.x >> 16);
    acc[2] += a * bf2f(u.y & 0xffff); acc[3] += a * bf2f(u.y >> 16);
    acc[4] += a * bf2f(u.z & 0xffff); acc[5] += a * bf2f(u.z >> 16);
    acc[6] += a * bf2f(u.w & 0xffff); acc[7] += a * bf2f(u.w >> 16);
  }
  unsigned int p[8];
  #pragma unroll
  for (int j = 0; j < 8; ++j) p[j] = f2bf(acc[j]);
  uint4 o4;
  o4.x = p[0] | (p[1] << 16); o4.y = p[2] | (p[3] << 16);
  o4.z = p[4] | (p[5] << 16); o4.w = p[6] | (p[7] << 16);
  *reinterpret_cast<uint4*>(upd + ((size_t)b * 16 + slot) * 512 + d) = o4;
}

// ---------------- host launch ----------------

extern "C" void kernel_launch(void* const* d_in, const int* in_sizes, int n_in,
                              void* d_out, int out_size, void* d_ws, size_t ws_size,
                              hipStream_t stream) {
  const float* inputs  = (const float*)d_in[0];
  const float* noise   = (const float*)d_in[1];
  const float* slot_mu = (const float*)d_in[2];
  const float* slot_ls = (const float*)d_in[3];
  const float* ln_in_g = (const float*)d_in[4];
  const float* ln_in_b = (const float*)d_in[5];
  const float* ln_s_g  = (const float*)d_in[6];
  const float* ln_s_b  = (const float*)d_in[7];
  const float* ln_m_g  = (const float*)d_in[8];
  const float* ln_m_b  = (const float*)d_in[9];
  const float* Wq   = (const float*)d_in[10];
  const float* Wk   = (const float*)d_in[11];
  const float* Wv   = (const float*)d_in[12];
  const float* w_ih = (const float*)d_in[13];
  const float* w_hh = (const float*)d_in[14];
  const float* b_ih = (const float*)d_in[15];
  const float* b_hh = (const float*)d_in[16];
  const float* w1   = (const float*)d_in[17];
  const float* b1   = (const float*)d_in[18];
  const float* w2   = (const float*)d_in[19];
  const float* b2   = (const float*)d_in[20];

  const int BN = 65536, BS = 1024, D = 512;

  uintptr_t base = (uintptr_t)d_ws;
  auto alloc = [&](size_t bytes) {
    void* p = (void*)base;
    base += (bytes + 255) & ~(size_t)255;
    return p;
  };
  unsigned short* x_bf    = (unsigned short*)alloc((size_t)BN * D * 2);
  unsigned short* kv_bf   = (unsigned short*)alloc((size_t)BN * 1024 * 2);
  unsigned short* wkv_bf  = (unsigned short*)alloc(1024 * 512 * 2);
  unsigned short* wih_bf  = (unsigned short*)alloc(1536 * 512 * 2);
  unsigned short* whh_bf  = (unsigned short*)alloc(1536 * 512 * 2);
  unsigned short* w1_bf   = (unsigned short*)alloc(512 * 512 * 2);
  unsigned short* w2_bf   = (unsigned short*)alloc(512 * 512 * 2);
  float*          slots   = (float*)alloc((size_t)BS * D * 4);
  unsigned short* slots_bf= (unsigned short*)alloc((size_t)BS * D * 2);
  unsigned short* sn_bf   = (unsigned short*)alloc((size_t)BS * D * 2);
  float*          logits  = (float*)alloc((size_t)64 * 16 * 1024 * 4);
  float*          attn_f  = (float*)alloc((size_t)64 * 16 * 1024 * 4);
  unsigned short* upd_bf  = (unsigned short*)alloc((size_t)BS * D * 2);
  float*          gi      = (float*)alloc((size_t)BS * 1536 * 4);
  float*          gh      = (float*)alloc((size_t)BS * 1536 * 4);
  float*          sgru    = (float*)alloc((size_t)BS * D * 4);
  unsigned short* lnm_bf  = (unsigned short*)alloc((size_t)BS * D * 2);
  unsigned short* h_bf    = (unsigned short*)alloc((size_t)BS * D * 2);
  (void)ws_size; (void)n_in; (void)in_sizes; (void)out_size;

  // weights: W' = Wq^T Wk folded into kv projection rows [0,512); Wv rows [512,1024)
  wcomp_k<<<dim3(2, 64), 256, 0, stream>>>(Wq, Wk, wkv_bf);
  cast_bf16_k<<<1024, 256, 0, stream>>>(Wv, wkv_bf + 262144, 262144);
  cast_bf16_k<<<3072, 256, 0, stream>>>(w_ih, wih_bf, 786432);
  cast_bf16_k<<<3072, 256, 0, stream>>>(w_hh, whh_bf, 786432);
  cast_bf16_k<<<1024, 256, 0, stream>>>(w1, w1_bf, 262144);
  cast_bf16_k<<<1024, 256, 0, stream>>>(w2, w2_bf, 262144);

  init_slots_k<<<2048, 256, 0, stream>>>(slot_mu, slot_ls, noise, slots);
  ln_rows_k<<<16384, 256, 0, stream>>>(inputs, ln_in_g, ln_in_b, x_bf, BN);
  gemm_bt<0,0,0,1><<<dim3(8, 512), 256, 0, stream>>>(
      x_bf, wkv_bf, nullptr, nullptr, kv_bf, BN, 1024, 512);

  for (int it = 0; it < 3; ++it) {
    ln_cast_k<<<256, 256, 0, stream>>>(slots, ln_s_g, ln_s_b, sn_bf, slots_bf);
    logits_k<<<dim3(16, 64), 256, 0, stream>>>(sn_bf, kv_bf, logits);
    softmax_cn_k<<<64, 1024, 0, stream>>>(logits, attn_f);
    updates_k<<<dim3(4, 64), 256, 0, stream>>>(attn_f, kv_bf, upd_bf);
    gemm_bt<1,0,0,0><<<dim3(12, 8), 256, 0, stream>>>(
        upd_bf, wih_bf, b_ih, nullptr, gi, BS, 1536, 512);
    gemm_bt<1,0,0,0><<<dim3(12, 8), 256, 0, stream>>>(
        slots_bf, whh_bf, b_hh, nullptr, gh, BS, 1536, 512);
    gru_ln_k<<<256, 256, 0, stream>>>(gi, gh, slots, ln_m_g, ln_m_b, sgru, lnm_bf);
    gemm_bt<1,1,0,1><<<dim3(4, 8), 256, 0, stream>>>(
        lnm_bf, w1_bf, b1, nullptr, h_bf, BS, 512, 512);
    float* slots_out = (it == 2) ? (float*)d_out : slots;
    gemm_bt<1,0,1,0><<<dim3(4, 8), 256, 0, stream>>>(
        h_bf, w2_bf, b2, sgru, slots_out, BS, 512, 512);
  }
}

// Round 4
// 635.596 us; speedup vs baseline: 1.2671x; 1.2468x over previous
//
#include <hip/hip_runtime.h>
#include <hip/hip_bf16.h>
#include <cstdint>
#include <cstddef>

// Shapes fixed: B=64, N=1024, D=512, S=16, 3 iterations.

typedef __bf16 bf16x8 __attribute__((ext_vector_type(8)));
typedef float f32x4 __attribute__((ext_vector_type(4)));

__device__ __forceinline__ float bf2f(unsigned int u) {
  union { unsigned int i; float f; } v; v.i = u << 16; return v.f;
}
__device__ __forceinline__ unsigned short f2bf(float x) {
  __hip_bfloat16 h = __float2bfloat16(x);
  unsigned short u;
  __builtin_memcpy(&u, &h, 2);
  return u;
}

#define GLD16(gp, lp)                                                       \
  __builtin_amdgcn_global_load_lds(                                         \
      (const __attribute__((address_space(1))) void*)(gp),                  \
      (__attribute__((address_space(3))) void*)(lp), 16, 0, 0)

// ---------------- elementwise / weight prep ----------------

__global__ void cast_bf16_k(const float* __restrict__ in, unsigned short* __restrict__ out, int n) {
  int i = blockIdx.x * 256 + threadIdx.x;
  if (i < n) out[i] = f2bf(in[i]);
}

__global__ void init_slots_k(const float* __restrict__ mu, const float* __restrict__ ls,
                             const float* __restrict__ noise, float* __restrict__ slots) {
  int i = blockIdx.x * 256 + threadIdx.x;
  int d = i & 511;
  slots[i] = mu[d] + expf(ls[d]) * noise[i];
}

// W'[e,k] = sum_d Wq[d,e] * Wk[d,k]  -> bf16 rows [0,512) of the kv weight
__global__ __launch_bounds__(256) void wcomp_k(const float* __restrict__ Wq,
                                               const float* __restrict__ Wk,
                                               unsigned short* __restrict__ Wout) {
  int kp = (blockIdx.x << 8) + threadIdx.x;  // grid.x = 2
  int e0 = blockIdx.y << 3;                  // grid.y = 64
  float acc[8] = {0.f, 0.f, 0.f, 0.f, 0.f, 0.f, 0.f, 0.f};
  for (int d = 0; d < 512; ++d) {
    float wk = Wk[d * 512 + kp];
    #pragma unroll
    for (int j = 0; j < 8; ++j) acc[j] += Wq[d * 512 + e0 + j] * wk;
  }
  #pragma unroll
  for (int j = 0; j < 8; ++j) Wout[(size_t)(e0 + j) * 512 + kp] = f2bf(acc[j]);
}

// Wcat [2048][1024]: rows j<1024: [wih[j] | whh[j]]; [1024,1536): [wih[j] | 0];
// [1536,2048): [0 | whh[j-512]]
__global__ void wcat_k(const float* __restrict__ wih, const float* __restrict__ whh,
                       unsigned short* __restrict__ out) {
  int i = blockIdx.x * 256 + threadIdx.x;  // 2M total
  int j = i >> 10, k = i & 1023;
  float v;
  if (j < 1024)      v = (k < 512) ? wih[j * 512 + k] : whh[j * 512 + (k - 512)];
  else if (j < 1536) v = (k < 512) ? wih[j * 512 + k] : 0.0f;
  else               v = (k < 512) ? 0.0f : whh[(j - 512) * 512 + (k - 512)];
  out[i] = f2bf(v);
}

__global__ void bcat_k(const float* __restrict__ bih, const float* __restrict__ bhh,
                       float* __restrict__ out) {
  int j = blockIdx.x * 256 + threadIdx.x;  // 2048
  float v;
  if (j < 1024)      v = bih[j] + bhh[j];
  else if (j < 1536) v = bih[j];
  else               v = bhh[j - 512];
  out[j] = v;
}

// ---------------- layernorm (wave per row, D=512) ----------------

__global__ __launch_bounds__(256) void ln_rows_k(
    const float* __restrict__ in, const float* __restrict__ g, const float* __restrict__ b,
    unsigned short* __restrict__ out, int rows) {
  int w = threadIdx.x >> 6, lane = threadIdx.x & 63;
  int row = (blockIdx.x << 2) + w;
  if (row >= rows) return;
  const float4* rp = reinterpret_cast<const float4*>(in + (size_t)row * 512);
  float4 v0 = rp[lane], v1 = rp[lane + 64];
  float s = v0.x + v0.y + v0.z + v0.w + v1.x + v1.y + v1.z + v1.w;
  float q = v0.x*v0.x + v0.y*v0.y + v0.z*v0.z + v0.w*v0.w
          + v1.x*v1.x + v1.y*v1.y + v1.z*v1.z + v1.w*v1.w;
  #pragma unroll
  for (int o = 32; o > 0; o >>= 1) { s += __shfl_xor(s, o); q += __shfl_xor(q, o); }
  float m = s * (1.0f / 512.0f);
  float rstd = rsqrtf(q * (1.0f / 512.0f) - m * m + 1e-8f);
  const float4* gp = reinterpret_cast<const float4*>(g);
  const float4* bp = reinterpret_cast<const float4*>(b);
  float4 g0 = gp[lane], g1 = gp[lane + 64];
  float4 b0 = bp[lane], b1 = bp[lane + 64];
  ushort4 o0, o1;
  o0.x = f2bf((v0.x - m) * rstd * g0.x + b0.x);
  o0.y = f2bf((v0.y - m) * rstd * g0.y + b0.y);
  o0.z = f2bf((v0.z - m) * rstd * g0.z + b0.z);
  o0.w = f2bf((v0.w - m) * rstd * g0.w + b0.w);
  o1.x = f2bf((v1.x - m) * rstd * g1.x + b1.x);
  o1.y = f2bf((v1.y - m) * rstd * g1.y + b1.y);
  o1.z = f2bf((v1.z - m) * rstd * g1.z + b1.z);
  o1.w = f2bf((v1.w - m) * rstd * g1.w + b1.w);
  ushort4* op = reinterpret_cast<ushort4*>(out + (size_t)row * 512);
  op[lane] = o0; op[lane + 64] = o1;
}

// LN(slots)->sn_bf AND raw cast slots -> A2 right half (row stride 1024)
__global__ __launch_bounds__(256) void ln_cast_k(
    const float* __restrict__ in, const float* __restrict__ g, const float* __restrict__ b,
    unsigned short* __restrict__ sn, unsigned short* __restrict__ A2) {
  int w = threadIdx.x >> 6, lane = threadIdx.x & 63;
  int row = (blockIdx.x << 2) + w;
  const float4* rp = reinterpret_cast<const float4*>(in + (size_t)row * 512);
  float4 v0 = rp[lane], v1 = rp[lane + 64];
  float s = v0.x + v0.y + v0.z + v0.w + v1.x + v1.y + v1.z + v1.w;
  float q = v0.x*v0.x + v0.y*v0.y + v0.z*v0.z + v0.w*v0.w
          + v1.x*v1.x + v1.y*v1.y + v1.z*v1.z + v1.w*v1.w;
  #pragma unroll
  for (int o = 32; o > 0; o >>= 1) { s += __shfl_xor(s, o); q += __shfl_xor(q, o); }
  float m = s * (1.0f / 512.0f);
  float rstd = rsqrtf(q * (1.0f / 512.0f) - m * m + 1e-8f);
  const float4* gp = reinterpret_cast<const float4*>(g);
  const float4* bp = reinterpret_cast<const float4*>(b);
  float4 g0 = gp[lane], g1 = gp[lane + 64];
  float4 b0 = bp[lane], b1 = bp[lane + 64];
  ushort4 c0, c1, o0, o1;
  c0.x = f2bf(v0.x); c0.y = f2bf(v0.y); c0.z = f2bf(v0.z); c0.w = f2bf(v0.w);
  c1.x = f2bf(v1.x); c1.y = f2bf(v1.y); c1.z = f2bf(v1.z); c1.w = f2bf(v1.w);
  o0.x = f2bf((v0.x - m) * rstd * g0.x + b0.x);
  o0.y = f2bf((v0.y - m) * rstd * g0.y + b0.y);
  o0.z = f2bf((v0.z - m) * rstd * g0.z + b0.z);
  o0.w = f2bf((v0.w - m) * rstd * g0.w + b0.w);
  o1.x = f2bf((v1.x - m) * rstd * g1.x + b1.x);
  o1.y = f2bf((v1.y - m) * rstd * g1.y + b1.y);
  o1.z = f2bf((v1.z - m) * rstd * g1.z + b1.z);
  o1.w = f2bf((v1.w - m) * rstd * g1.w + b1.w);
  ushort4* sp_ = reinterpret_cast<ushort4*>(sn + (size_t)row * 512);
  ushort4* cp_ = reinterpret_cast<ushort4*>(A2 + (size_t)row * 1024 + 512);
  sp_[lane] = o0; sp_[lane + 64] = o1;
  cp_[lane] = c0; cp_[lane + 64] = c1;
}

// GRU (fused-gates layout) + LN: gates[row][2048] = [rsum, zsum, i_n, h_n]
__global__ __launch_bounds__(256) void gru_ln_k(
    const float* __restrict__ gates, const float* __restrict__ hp,
    const float* __restrict__ g, const float* __restrict__ b,
    float* __restrict__ sgru, unsigned short* __restrict__ lnm) {
  int w = threadIdx.x >> 6, lane = threadIdx.x & 63;
  int row = (blockIdx.x << 2) + w;
  size_t gb = (size_t)row * 2048 + (lane << 3);
  size_t hb = (size_t)row * 512 + (lane << 3);
  float rs[8], zs[8], in_[8], hn[8], hv[8], y[8];
  #pragma unroll
  for (int c = 0; c < 2; ++c) {
    *reinterpret_cast<float4*>(rs + 4*c)  = *reinterpret_cast<const float4*>(gates + gb + 4*c);
    *reinterpret_cast<float4*>(zs + 4*c)  = *reinterpret_cast<const float4*>(gates + gb + 512 + 4*c);
    *reinterpret_cast<float4*>(in_ + 4*c) = *reinterpret_cast<const float4*>(gates + gb + 1024 + 4*c);
    *reinterpret_cast<float4*>(hn + 4*c)  = *reinterpret_cast<const float4*>(gates + gb + 1536 + 4*c);
    *reinterpret_cast<float4*>(hv + 4*c)  = *reinterpret_cast<const float4*>(hp + hb + 4*c);
  }
  float s = 0.f, q = 0.f;
  #pragma unroll
  for (int j = 0; j < 8; ++j) {
    float r = 1.0f / (1.0f + expf(-rs[j]));
    float z = 1.0f / (1.0f + expf(-zs[j]));
    float n = tanhf(in_[j] + r * hn[j]);
    float h = (1.0f - z) * n + z * hv[j];
    y[j] = h; s += h; q += h * h;
  }
  #pragma unroll
  for (int o = 32; o > 0; o >>= 1) { s += __shfl_xor(s, o); q += __shfl_xor(q, o); }
  float m = s * (1.0f / 512.0f);
  float rstd = rsqrtf(q * (1.0f / 512.0f) - m * m + 1e-8f);
  const float* gg = g + (lane << 3);
  const float* bb = b + (lane << 3);
  #pragma unroll
  for (int c = 0; c < 2; ++c)
    *reinterpret_cast<float4*>(sgru + hb + 4*c) = *reinterpret_cast<const float4*>(y + 4*c);
  uint4 o4;
  unsigned int p[8];
  #pragma unroll
  for (int j = 0; j < 8; ++j) p[j] = f2bf((y[j] - m) * rstd * gg[j] + bb[j]);
  o4.x = p[0] | (p[1] << 16); o4.y = p[2] | (p[3] << 16);
  o4.z = p[4] | (p[5] << 16); o4.w = p[6] | (p[7] << 16);
  *reinterpret_cast<uint4*>(lnm + hb) = o4;
}

// ---------------- MFMA GEMM 128x128 (kv projection) ----------------
// C[M,N] = A[M,K] @ W[N,K]^T. BK=32, 4 waves of 64x64, gload_lds 2-buffer.

template<int BIAS, int RELU, int ADDSRC, int OUTBF16>
__global__ __launch_bounds__(256) void gemm_bt(
    const unsigned short* __restrict__ A, const unsigned short* __restrict__ W,
    const float* __restrict__ bias, const float* __restrict__ addsrc,
    void* __restrict__ Cout, int M, int N, int K) {
  __shared__ unsigned short sA[2][4096];  // [128][32] linear
  __shared__ unsigned short sB[2][4096];
  const int tid = threadIdx.x;
  const int lane = tid & 63, w = tid >> 6;

  int nwg = gridDim.x * gridDim.y;
  int flat = blockIdx.y * gridDim.x + blockIdx.x;
  if ((nwg & 7) == 0) { int c = nwg >> 3; flat = (flat & 7) * c + (flat >> 3); }
  const int row0 = (flat / gridDim.x) << 7;
  const int col0 = (flat % gridDim.x) << 7;

  const int wm = (w >> 1) << 6, wn = (w & 1) << 6;
  const int lrow = lane & 15, kt = (lane >> 4) << 3;
  const int srow = lane >> 2, scol = (lane & 3) << 3;

  f32x4 acc[4][4];
  #pragma unroll
  for (int m = 0; m < 4; ++m)
    #pragma unroll
    for (int n = 0; n < 4; ++n) acc[m][n] = f32x4{0.f, 0.f, 0.f, 0.f};

  auto stage = [&](int buf, int k0) {
    #pragma unroll
    for (int i = 0; i < 2; ++i) {
      int ii = w * 2 + i;
      int r = (ii << 4) + srow;
      GLD16(A + (size_t)(row0 + r) * K + k0 + scol, &sA[buf][ii * 512]);
      GLD16(W + (size_t)(col0 + r) * K + k0 + scol, &sB[buf][ii * 512]);
    }
  };

  stage(0, 0);
  const int nt = K >> 5;
  int cur = 0;
  for (int t = 0; t < nt; ++t) {
    __syncthreads();
    if (t + 1 < nt) stage(cur ^ 1, (t + 1) << 5);
    bf16x8 af[4], bfv[4];
    #pragma unroll
    for (int m = 0; m < 4; ++m)
      af[m] = *reinterpret_cast<const bf16x8*>(&sA[cur][(wm + m * 16 + lrow) * 32 + kt]);
    #pragma unroll
    for (int n = 0; n < 4; ++n)
      bfv[n] = *reinterpret_cast<const bf16x8*>(&sB[cur][(wn + n * 16 + lrow) * 32 + kt]);
    #pragma unroll
    for (int m = 0; m < 4; ++m)
      #pragma unroll
      for (int n = 0; n < 4; ++n)
        acc[m][n] = __builtin_amdgcn_mfma_f32_16x16x32_bf16(af[m], bfv[n], acc[m][n], 0, 0, 0);
    cur ^= 1;
  }

  const int rb = (lane >> 4) << 2;
  #pragma unroll
  for (int m = 0; m < 4; ++m) {
    #pragma unroll
    for (int n = 0; n < 4; ++n) {
      int col = col0 + wn + n * 16 + lrow;
      float bv = BIAS ? bias[col] : 0.0f;
      #pragma unroll
      for (int r = 0; r < 4; ++r) {
        int row = row0 + wm + m * 16 + rb + r;
        float v = acc[m][n][r] + bv;
        if (ADDSRC) v += addsrc[(size_t)row * N + col];
        if (RELU) v = fmaxf(v, 0.0f);
        if (OUTBF16) ((unsigned short*)Cout)[(size_t)row * N + col] = f2bf(v);
        else ((float*)Cout)[(size_t)row * N + col] = v;
      }
    }
  }
}

// ---------------- MFMA GEMM 64x64 (slot-sized GEMMs; more blocks) ----------------
// 4 waves; wave w owns cols [w*16, w*16+16), all 64 rows. 4 MFMA/K-step.

template<int BIAS, int RELU, int ADDSRC, int OUTBF16>
__global__ __launch_bounds__(256) void gemm_sm(
    const unsigned short* __restrict__ A, const unsigned short* __restrict__ W,
    const float* __restrict__ bias, const float* __restrict__ addsrc,
    void* __restrict__ Cout, int M, int N, int K) {
  __shared__ unsigned short sA[2][2048];  // [64][32] linear
  __shared__ unsigned short sB[2][2048];
  const int tid = threadIdx.x;
  const int lane = tid & 63, w = tid >> 6;

  int nwg = gridDim.x * gridDim.y;
  int flat = blockIdx.y * gridDim.x + blockIdx.x;
  if ((nwg & 7) == 0) { int c = nwg >> 3; flat = (flat & 7) * c + (flat >> 3); }
  const int row0 = (flat / gridDim.x) << 6;
  const int col0 = (flat % gridDim.x) << 6;

  const int lrow = lane & 15, kt = (lane >> 4) << 3;
  const int srow = lane >> 2, scol = (lane & 3) << 3;

  f32x4 acc[4];
  #pragma unroll
  for (int m = 0; m < 4; ++m) acc[m] = f32x4{0.f, 0.f, 0.f, 0.f};

  auto stage = [&](int buf, int k0) {
    int r = (w << 4) + srow;
    GLD16(A + (size_t)(row0 + r) * K + k0 + scol, &sA[buf][w * 512]);
    GLD16(W + (size_t)(col0 + r) * K + k0 + scol, &sB[buf][w * 512]);
  };

  stage(0, 0);
  const int nt = K >> 5;
  int cur = 0;
  for (int t = 0; t < nt; ++t) {
    __syncthreads();
    if (t + 1 < nt) stage(cur ^ 1, (t + 1) << 5);
    bf16x8 af[4], bfv;
    #pragma unroll
    for (int m = 0; m < 4; ++m)
      af[m] = *reinterpret_cast<const bf16x8*>(&sA[cur][(m * 16 + lrow) * 32 + kt]);
    bfv = *reinterpret_cast<const bf16x8*>(&sB[cur][((w << 4) + lrow) * 32 + kt]);
    #pragma unroll
    for (int m = 0; m < 4; ++m)
      acc[m] = __builtin_amdgcn_mfma_f32_16x16x32_bf16(af[m], bfv, acc[m], 0, 0, 0);
    cur ^= 1;
  }

  const int rb = (lane >> 4) << 2;
  const int col = col0 + (w << 4) + lrow;
  float bv = BIAS ? bias[col] : 0.0f;
  #pragma unroll
  for (int m = 0; m < 4; ++m) {
    #pragma unroll
    for (int r = 0; r < 4; ++r) {
      int row = row0 + m * 16 + rb + r;
      float v = acc[m][r] + bv;
      if (ADDSRC) v += addsrc[(size_t)row * N + col];
      if (RELU) v = fmaxf(v, 0.0f);
      if (OUTBF16) ((unsigned short*)Cout)[(size_t)row * N + col] = f2bf(v);
      else ((float*)Cout)[(size_t)row * N + col] = v;
    }
  }
}

// ---------------- logits[b,s,n] = scale * sn[b,s,:]·k2[b,n,:] ----------------

__global__ __launch_bounds__(256) void logits_k(
    const unsigned short* __restrict__ sn, const unsigned short* __restrict__ kv,
    float* __restrict__ out) {
  __shared__ float sq[16][512];
  int b = blockIdx.y, nc = blockIdx.x;
  for (int i = threadIdx.x; i < 8192; i += 256)
    sq[i >> 9][i & 511] = bf2f(sn[((size_t)b << 13) + i]);
  __syncthreads();
  int nl = threadIdx.x & 63, sg = threadIdx.x >> 6;
  int n = (nc << 6) + nl;
  const unsigned short* kr = kv + (((size_t)b << 10) + n) * 1024;
  const float* s0 = sq[sg * 4 + 0];
  const float* s1 = sq[sg * 4 + 1];
  const float* s2 = sq[sg * 4 + 2];
  const float* s3 = sq[sg * 4 + 3];
  float a0 = 0.f, a1 = 0.f, a2 = 0.f, a3 = 0.f;
  for (int k0 = 0; k0 < 512; k0 += 8) {
    uint4 u = *reinterpret_cast<const uint4*>(kr + k0);
    float kf[8];
    kf[0] = bf2f(u.x & 0xffff); kf[1] = bf2f(u.x >> 16);
    kf[2] = bf2f(u.y & 0xffff); kf[3] = bf2f(u.y >> 16);
    kf[4] = bf2f(u.z & 0xffff); kf[5] = bf2f(u.z >> 16);
    kf[6] = bf2f(u.w & 0xffff); kf[7] = bf2f(u.w >> 16);
    #pragma unroll
    for (int e = 0; e < 8; ++e) {
      a0 += kf[e] * s0[k0 + e];
      a1 += kf[e] * s1[k0 + e];
      a2 += kf[e] * s2[k0 + e];
      a3 += kf[e] * s3[k0 + e];
    }
  }
  const float scale = 0.044194173824159216f;
  float* ob = out + ((size_t)b << 14) + ((size_t)(sg * 4)) * 1024 + n;
  ob[0] = a0 * scale; ob[1024] = a1 * scale; ob[2048] = a2 * scale; ob[3072] = a3 * scale;
}

// ---------------- softmax over n, column-normalize over s; f32 out ----------------

__global__ __launch_bounds__(1024) void softmax_cn_k(
    const float* __restrict__ logits, float* __restrict__ attn) {
  __shared__ float sp[16][1024];
  int b = blockIdx.x;
  int w = threadIdx.x >> 6, lane = threadIdx.x & 63;
  const float* rp = logits + ((size_t)b * 16 + w) * 1024;
  float v[16];
  float mx = -3.4e38f;
  #pragma unroll
  for (int i = 0; i < 16; ++i) { v[i] = rp[lane + (i << 6)]; mx = fmaxf(mx, v[i]); }
  #pragma unroll
  for (int o = 32; o > 0; o >>= 1) mx = fmaxf(mx, __shfl_xor(mx, o));
  float s = 0.f;
  #pragma unroll
  for (int i = 0; i < 16; ++i) { v[i] = __expf(v[i] - mx); s += v[i]; }
  #pragma unroll
  for (int o = 32; o > 0; o >>= 1) s += __shfl_xor(s, o);
  float inv = 1.0f / s;
  #pragma unroll
  for (int i = 0; i < 16; ++i) sp[w][lane + (i << 6)] = v[i] * inv;
  __syncthreads();
  int col = threadIdx.x;
  float cs = 0.f;
  #pragma unroll
  for (int s2 = 0; s2 < 16; ++s2) cs += sp[s2][col];
  float rinv = 1.0f / (cs + 1e-8f);
  float* ob = attn + ((size_t)b << 14);
  #pragma unroll
  for (int s2 = 0; s2 < 16; ++s2) ob[s2 * 1024 + col] = sp[s2][col] * rinv;
}

// ---------------- updates split-K: partial[b][c][s][d] over n-window 256 ----------------
// grid (4, 64); block 256: 64 d-lanes (8 d each) x 4 slot-groups (4 s each)

__global__ __launch_bounds__(256) void upd_part_k(
    const float* __restrict__ attn, const unsigned short* __restrict__ kv,
    float* __restrict__ partial) {
  __shared__ float sa[16][256];
  int b = blockIdx.y, nc = blockIdx.x;
  for (int i = threadIdx.x; i < 4096; i += 256)
    sa[i >> 8][i & 255] = attn[((size_t)b << 14) + (i >> 8) * 1024 + (nc << 8) + (i & 255)];
  __syncthreads();
  int dl = threadIdx.x & 63, sg = threadIdx.x >> 6;
  const unsigned short* vb = kv + (((size_t)(b << 10) + (nc << 8)) << 10) + 512 + (dl << 3);
  float acc[4][8];
  #pragma unroll
  for (int s = 0; s < 4; ++s)
    #pragma unroll
    for (int j = 0; j < 8; ++j) acc[s][j] = 0.f;
  for (int n = 0; n < 256; ++n) {
    uint4 u = *reinterpret_cast<const uint4*>(vb + ((size_t)n << 10));
    float vf[8];
    vf[0] = bf2f(u.x & 0xffff); vf[1] = bf2f(u.x >> 16);
    vf[2] = bf2f(u.y & 0xffff); vf[3] = bf2f(u.y >> 16);
    vf[4] = bf2f(u.z & 0xffff); vf[5] = bf2f(u.z >> 16);
    vf[6] = bf2f(u.w & 0xffff); vf[7] = bf2f(u.w >> 16);
    #pragma unroll
    for (int s = 0; s < 4; ++s) {
      float a = sa[sg * 4 + s][n];
      #pragma unroll
      for (int j = 0; j < 8; ++j) acc[s][j] += a * vf[j];
    }
  }
  #pragma unroll
  for (int s = 0; s < 4; ++s) {
    float* pb = partial + (((size_t)(b * 4 + nc) * 16) + sg * 4 + s) * 512 + (dl << 3);
    *reinterpret_cast<float4*>(pb)     = *reinterpret_cast<float4*>(&acc[s][0]);
    *reinterpret_cast<float4*>(pb + 4) = *reinterpret_cast<float4*>(&acc[s][4]);
  }
}

// reduce 4 partials -> bf16 into A2 left half (cols [0,512), row stride 1024)
__global__ __launch_bounds__(256) void upd_red_k(
    const float* __restrict__ partial, unsigned short* __restrict__ A2) {
  int o = blockIdx.x * 256 + threadIdx.x;  // 131072 float4-outputs
  int row = o >> 7, d0 = (o & 127) << 2;
  int b = row >> 4, s = row & 15;
  float4 acc = {0.f, 0.f, 0.f, 0.f};
  #pragma unroll
  for (int c = 0; c < 4; ++c) {
    float4 p = *reinterpret_cast<const float4*>(
        partial + (((size_t)(b * 4 + c) * 16) + s) * 512 + d0);
    acc.x += p.x; acc.y += p.y; acc.z += p.z; acc.w += p.w;
  }
  uint2 u;
  u.x = (unsigned)f2bf(acc.x) | ((unsigned)f2bf(acc.y) << 16);
  u.y = (unsigned)f2bf(acc.z) | ((unsigned)f2bf(acc.w) << 16);
  *reinterpret_cast<uint2*>(A2 + (size_t)row * 1024 + d0) = u;
}

// ---------------- host launch ----------------

extern "C" void kernel_launch(void* const* d_in, const int* in_sizes, int n_in,
                              void* d_out, int out_size, void* d_ws, size_t ws_size,
                              hipStream_t stream) {
  const float* inputs  = (const float*)d_in[0];
  const float* noise   = (const float*)d_in[1];
  const float* slot_mu = (const float*)d_in[2];
  const float* slot_ls = (const float*)d_in[3];
  const float* ln_in_g = (const float*)d_in[4];
  const float* ln_in_b = (const float*)d_in[5];
  const float* ln_s_g  = (const float*)d_in[6];
  const float* ln_s_b  = (const float*)d_in[7];
  const float* ln_m_g  = (const float*)d_in[8];
  const float* ln_m_b  = (const float*)d_in[9];
  const float* Wq   = (const float*)d_in[10];
  const float* Wk   = (const float*)d_in[11];
  const float* Wv   = (const float*)d_in[12];
  const float* w_ih = (const float*)d_in[13];
  const float* w_hh = (const float*)d_in[14];
  const float* b_ih = (const float*)d_in[15];
  const float* b_hh = (const float*)d_in[16];
  const float* w1   = (const float*)d_in[17];
  const float* b1   = (const float*)d_in[18];
  const float* w2   = (const float*)d_in[19];
  const float* b2   = (const float*)d_in[20];

  const int BN = 65536, BS = 1024;

  uintptr_t base = (uintptr_t)d_ws;
  auto alloc = [&](size_t bytes) {
    void* p = (void*)base;
    base += (bytes + 255) & ~(size_t)255;
    return p;
  };
  unsigned short* x_bf    = (unsigned short*)alloc((size_t)BN * 512 * 2);
  unsigned short* kv_bf   = (unsigned short*)alloc((size_t)BN * 1024 * 2);
  unsigned short* wkv_bf  = (unsigned short*)alloc(1024 * 512 * 2);
  unsigned short* wcat_bf = (unsigned short*)alloc((size_t)2048 * 1024 * 2);
  float*          bcat    = (float*)alloc(2048 * 4);
  unsigned short* w1_bf   = (unsigned short*)alloc(512 * 512 * 2);
  unsigned short* w2_bf   = (unsigned short*)alloc(512 * 512 * 2);
  float*          slots   = (float*)alloc((size_t)BS * 512 * 4);
  unsigned short* sn_bf   = (unsigned short*)alloc((size_t)BS * 512 * 2);
  unsigned short* A2      = (unsigned short*)alloc((size_t)BS * 1024 * 2);
  float*          logits  = (float*)alloc((size_t)64 * 16 * 1024 * 4);
  float*          attn_f  = (float*)alloc((size_t)64 * 16 * 1024 * 4);
  float*          gates   = (float*)alloc((size_t)BS * 2048 * 4);  // aliased: partial
  float*          partial = gates;  // [64][4][16][512] f32 = 8MB, consumed before gates written
  float*          sgru    = (float*)alloc((size_t)BS * 512 * 4);
  unsigned short* lnm_bf  = (unsigned short*)alloc((size_t)BS * 512 * 2);
  unsigned short* h_bf    = (unsigned short*)alloc((size_t)BS * 512 * 2);
  (void)ws_size; (void)n_in; (void)in_sizes; (void)out_size;

  // weight prep
  wcomp_k<<<dim3(2, 64), 256, 0, stream>>>(Wq, Wk, wkv_bf);
  cast_bf16_k<<<1024, 256, 0, stream>>>(Wv, wkv_bf + 262144, 262144);
  wcat_k<<<8192, 256, 0, stream>>>(w_ih, w_hh, wcat_bf);
  bcat_k<<<8, 256, 0, stream>>>(b_ih, b_hh, bcat);
  cast_bf16_k<<<1024, 256, 0, stream>>>(w1, w1_bf, 262144);
  cast_bf16_k<<<1024, 256, 0, stream>>>(w2, w2_bf, 262144);

  init_slots_k<<<2048, 256, 0, stream>>>(slot_mu, slot_ls, noise, slots);
  ln_rows_k<<<16384, 256, 0, stream>>>(inputs, ln_in_g, ln_in_b, x_bf, BN);
  gemm_bt<0,0,0,1><<<dim3(8, 512), 256, 0, stream>>>(
      x_bf, wkv_bf, nullptr, nullptr, kv_bf, BN, 1024, 512);

  for (int it = 0; it < 3; ++it) {
    ln_cast_k<<<256, 256, 0, stream>>>(slots, ln_s_g, ln_s_b, sn_bf, A2);
    logits_k<<<dim3(16, 64), 256, 0, stream>>>(sn_bf, kv_bf, logits);
    softmax_cn_k<<<64, 1024, 0, stream>>>(logits, attn_f);
    upd_part_k<<<dim3(4, 64), 256, 0, stream>>>(attn_f, kv_bf, partial);
    upd_red_k<<<512, 256, 0, stream>>>(partial, A2);
    gemm_sm<1,0,0,0><<<dim3(32, 16), 256, 0, stream>>>(
        A2, wcat_bf, bcat, nullptr, gates, BS, 2048, 1024);
    gru_ln_k<<<256, 256, 0, stream>>>(gates, slots, ln_m_g, ln_m_b, sgru, lnm_bf);
    gemm_sm<1,1,0,1><<<dim3(8, 16), 256, 0, stream>>>(
        lnm_bf, w1_bf, b1, nullptr, h_bf, BS, 512, 512);
    float* slots_out = (it == 2) ? (float*)d_out : slots;
    gemm_sm<1,0,1,0><<<dim3(8, 16), 256, 0, stream>>>(
        h_bf, w2_bf, b2, sgru, slots_out, BS, 512, 512);
  }
}

// Round 5
// 460.972 us; speedup vs baseline: 1.7471x; 1.3788x over previous
//
#include <hip/hip_runtime.h>
#include <hip/hip_bf16.h>
#include <cstdint>
#include <cstddef>

// Shapes fixed: B=64, N=1024, D=512, S=16, 3 iterations.
// Algebra: logits = sn·W'·x^T with W' = scale·Wq^T·Wk  (k never materialized)
//          updates^T = vT_b @ attn_b^T  (vT stored transposed per batch)

typedef __bf16 bf16x8 __attribute__((ext_vector_type(8)));
typedef float f32x4 __attribute__((ext_vector_type(4)));

__device__ __forceinline__ float bf2f(unsigned int u) {
  union { unsigned int i; float f; } v; v.i = u << 16; return v.f;
}
__device__ __forceinline__ unsigned short f2bf(float x) {
  __hip_bfloat16 h = __float2bfloat16(x);
  unsigned short u;
  __builtin_memcpy(&u, &h, 2);
  return u;
}

#define GLD16(gp, lp)                                                       \
  __builtin_amdgcn_global_load_lds(                                         \
      (const __attribute__((address_space(1))) void*)(gp),                  \
      (__attribute__((address_space(3))) void*)(lp), 16, 0, 0)

// ---------------- elementwise / weight prep ----------------

__global__ void cast_bf16_k(const float* __restrict__ in, unsigned short* __restrict__ out, int n) {
  int i = blockIdx.x * 256 + threadIdx.x;
  if (i < n) out[i] = f2bf(in[i]);
}

__global__ void init_slots_k(const float* __restrict__ mu, const float* __restrict__ ls,
                             const float* __restrict__ noise, float* __restrict__ slots) {
  int i = blockIdx.x * 256 + threadIdx.x;
  int d = i & 511;
  slots[i] = mu[d] + expf(ls[d]) * noise[i];
}

// W'T[kp][e] = scale * sum_d Wq[d,e] * Wk[d,kp]   (transposed + scale folded)
__global__ __launch_bounds__(256) void wcomp_k(const float* __restrict__ Wq,
                                               const float* __restrict__ Wk,
                                               unsigned short* __restrict__ Wout) {
  int kp = (blockIdx.x << 8) + threadIdx.x;  // grid.x = 2
  int e0 = blockIdx.y << 3;                  // grid.y = 64
  float acc[8] = {0.f, 0.f, 0.f, 0.f, 0.f, 0.f, 0.f, 0.f};
  for (int d = 0; d < 512; ++d) {
    float wk = Wk[d * 512 + kp];
    #pragma unroll
    for (int j = 0; j < 8; ++j) acc[j] += Wq[d * 512 + e0 + j] * wk;
  }
  const float scale = 0.044194173824159216f;  // 512^-0.5
  unsigned int p[8];
  #pragma unroll
  for (int j = 0; j < 8; ++j) p[j] = f2bf(acc[j] * scale);
  uint4 o;
  o.x = p[0] | (p[1] << 16); o.y = p[2] | (p[3] << 16);
  o.z = p[4] | (p[5] << 16); o.w = p[6] | (p[7] << 16);
  *reinterpret_cast<uint4*>(Wout + (size_t)kp * 512 + e0) = o;
}

// Wcat [2048][1024]: rows j<1024: [wih[j] | whh[j]]; [1024,1536): [wih[j] | 0];
// [1536,2048): [0 | whh[j-512]]
__global__ void wcat_k(const float* __restrict__ wih, const float* __restrict__ whh,
                       unsigned short* __restrict__ out) {
  int i = blockIdx.x * 256 + threadIdx.x;  // 2M total
  int j = i >> 10, k = i & 1023;
  float v;
  if (j < 1024)      v = (k < 512) ? wih[j * 512 + k] : whh[j * 512 + (k - 512)];
  else if (j < 1536) v = (k < 512) ? wih[j * 512 + k] : 0.0f;
  else               v = (k < 512) ? 0.0f : whh[(j - 512) * 512 + (k - 512)];
  out[i] = f2bf(v);
}

__global__ void bcat_k(const float* __restrict__ bih, const float* __restrict__ bhh,
                       float* __restrict__ out) {
  int j = blockIdx.x * 256 + threadIdx.x;  // 2048
  float v;
  if (j < 1024)      v = bih[j] + bhh[j];
  else if (j < 1536) v = bih[j];
  else               v = bhh[j - 512];
  out[j] = v;
}

// ---------------- layernorm (wave per row, D=512) ----------------

__global__ __launch_bounds__(256) void ln_rows_k(
    const float* __restrict__ in, const float* __restrict__ g, const float* __restrict__ b,
    unsigned short* __restrict__ out, int rows) {
  int w = threadIdx.x >> 6, lane = threadIdx.x & 63;
  int row = (blockIdx.x << 2) + w;
  if (row >= rows) return;
  const float4* rp = reinterpret_cast<const float4*>(in + (size_t)row * 512);
  float4 v0 = rp[lane], v1 = rp[lane + 64];
  float s = v0.x + v0.y + v0.z + v0.w + v1.x + v1.y + v1.z + v1.w;
  float q = v0.x*v0.x + v0.y*v0.y + v0.z*v0.z + v0.w*v0.w
          + v1.x*v1.x + v1.y*v1.y + v1.z*v1.z + v1.w*v1.w;
  #pragma unroll
  for (int o = 32; o > 0; o >>= 1) { s += __shfl_xor(s, o); q += __shfl_xor(q, o); }
  float m = s * (1.0f / 512.0f);
  float rstd = rsqrtf(q * (1.0f / 512.0f) - m * m + 1e-8f);
  const float4* gp = reinterpret_cast<const float4*>(g);
  const float4* bp = reinterpret_cast<const float4*>(b);
  float4 g0 = gp[lane], g1 = gp[lane + 64];
  float4 b0 = bp[lane], b1 = bp[lane + 64];
  ushort4 o0, o1;
  o0.x = f2bf((v0.x - m) * rstd * g0.x + b0.x);
  o0.y = f2bf((v0.y - m) * rstd * g0.y + b0.y);
  o0.z = f2bf((v0.z - m) * rstd * g0.z + b0.z);
  o0.w = f2bf((v0.w - m) * rstd * g0.w + b0.w);
  o1.x = f2bf((v1.x - m) * rstd * g1.x + b1.x);
  o1.y = f2bf((v1.y - m) * rstd * g1.y + b1.y);
  o1.z = f2bf((v1.z - m) * rstd * g1.z + b1.z);
  o1.w = f2bf((v1.w - m) * rstd * g1.w + b1.w);
  ushort4* op = reinterpret_cast<ushort4*>(out + (size_t)row * 512);
  op[lane] = o0; op[lane + 64] = o1;
}

// LN(slots)->sn_bf AND raw cast slots -> A2 right half (row stride 1024)
__global__ __launch_bounds__(256) void ln_cast_k(
    const float* __restrict__ in, const float* __restrict__ g, const float* __restrict__ b,
    unsigned short* __restrict__ sn, unsigned short* __restrict__ A2) {
  int w = threadIdx.x >> 6, lane = threadIdx.x & 63;
  int row = (blockIdx.x << 2) + w;
  const float4* rp = reinterpret_cast<const float4*>(in + (size_t)row * 512);
  float4 v0 = rp[lane], v1 = rp[lane + 64];
  float s = v0.x + v0.y + v0.z + v0.w + v1.x + v1.y + v1.z + v1.w;
  float q = v0.x*v0.x + v0.y*v0.y + v0.z*v0.z + v0.w*v0.w
          + v1.x*v1.x + v1.y*v1.y + v1.z*v1.z + v1.w*v1.w;
  #pragma unroll
  for (int o = 32; o > 0; o >>= 1) { s += __shfl_xor(s, o); q += __shfl_xor(q, o); }
  float m = s * (1.0f / 512.0f);
  float rstd = rsqrtf(q * (1.0f / 512.0f) - m * m + 1e-8f);
  const float4* gp = reinterpret_cast<const float4*>(g);
  const float4* bp = reinterpret_cast<const float4*>(b);
  float4 g0 = gp[lane], g1 = gp[lane + 64];
  float4 b0 = bp[lane], b1 = bp[lane + 64];
  ushort4 c0, c1, o0, o1;
  c0.x = f2bf(v0.x); c0.y = f2bf(v0.y); c0.z = f2bf(v0.z); c0.w = f2bf(v0.w);
  c1.x = f2bf(v1.x); c1.y = f2bf(v1.y); c1.z = f2bf(v1.z); c1.w = f2bf(v1.w);
  o0.x = f2bf((v0.x - m) * rstd * g0.x + b0.x);
  o0.y = f2bf((v0.y - m) * rstd * g0.y + b0.y);
  o0.z = f2bf((v0.z - m) * rstd * g0.z + b0.z);
  o0.w = f2bf((v0.w - m) * rstd * g0.w + b0.w);
  o1.x = f2bf((v1.x - m) * rstd * g1.x + b1.x);
  o1.y = f2bf((v1.y - m) * rstd * g1.y + b1.y);
  o1.z = f2bf((v1.z - m) * rstd * g1.z + b1.z);
  o1.w = f2bf((v1.w - m) * rstd * g1.w + b1.w);
  ushort4* sp_ = reinterpret_cast<ushort4*>(sn + (size_t)row * 512);
  ushort4* cp_ = reinterpret_cast<ushort4*>(A2 + (size_t)row * 1024 + 512);
  sp_[lane] = o0; sp_[lane + 64] = o1;
  cp_[lane] = c0; cp_[lane + 64] = c1;
}

// GRU (fused-gates layout) + LN: gates[row][2048] = [rsum, zsum, i_n, h_n]
__global__ __launch_bounds__(256) void gru_ln_k(
    const float* __restrict__ gates, const float* __restrict__ hp,
    const float* __restrict__ g, const float* __restrict__ b,
    float* __restrict__ sgru, unsigned short* __restrict__ lnm) {
  int w = threadIdx.x >> 6, lane = threadIdx.x & 63;
  int row = (blockIdx.x << 2) + w;
  size_t gb = (size_t)row * 2048 + (lane << 3);
  size_t hb = (size_t)row * 512 + (lane << 3);
  float rs[8], zs[8], in_[8], hn[8], hv[8], y[8];
  #pragma unroll
  for (int c = 0; c < 2; ++c) {
    *reinterpret_cast<float4*>(rs + 4*c)  = *reinterpret_cast<const float4*>(gates + gb + 4*c);
    *reinterpret_cast<float4*>(zs + 4*c)  = *reinterpret_cast<const float4*>(gates + gb + 512 + 4*c);
    *reinterpret_cast<float4*>(in_ + 4*c) = *reinterpret_cast<const float4*>(gates + gb + 1024 + 4*c);
    *reinterpret_cast<float4*>(hn + 4*c)  = *reinterpret_cast<const float4*>(gates + gb + 1536 + 4*c);
    *reinterpret_cast<float4*>(hv + 4*c)  = *reinterpret_cast<const float4*>(hp + hb + 4*c);
  }
  float s = 0.f, q = 0.f;
  #pragma unroll
  for (int j = 0; j < 8; ++j) {
    float r = 1.0f / (1.0f + expf(-rs[j]));
    float z = 1.0f / (1.0f + expf(-zs[j]));
    float n = tanhf(in_[j] + r * hn[j]);
    float h = (1.0f - z) * n + z * hv[j];
    y[j] = h; s += h; q += h * h;
  }
  #pragma unroll
  for (int o = 32; o > 0; o >>= 1) { s += __shfl_xor(s, o); q += __shfl_xor(q, o); }
  float m = s * (1.0f / 512.0f);
  float rstd = rsqrtf(q * (1.0f / 512.0f) - m * m + 1e-8f);
  const float* gg = g + (lane << 3);
  const float* bb = b + (lane << 3);
  #pragma unroll
  for (int c = 0; c < 2; ++c)
    *reinterpret_cast<float4*>(sgru + hb + 4*c) = *reinterpret_cast<const float4*>(y + 4*c);
  uint4 o4;
  unsigned int p[8];
  #pragma unroll
  for (int j = 0; j < 8; ++j) p[j] = f2bf((y[j] - m) * rstd * gg[j] + bb[j]);
  o4.x = p[0] | (p[1] << 16); o4.y = p[2] | (p[3] << 16);
  o4.z = p[4] | (p[5] << 16); o4.w = p[6] | (p[7] << 16);
  *reinterpret_cast<uint4*>(lnm + hb) = o4;
}

// ---------------- gemm_vt: vT[b][d][n] = (x @ Wv^T) transposed per b ----------------
// A = x [65536][512], W = wv [512][512]. 128x128 tile, grid (4, 512).

__global__ __launch_bounds__(256) void gemm_vt(
    const unsigned short* __restrict__ A, const unsigned short* __restrict__ W,
    unsigned short* __restrict__ vT) {
  __shared__ unsigned short sA[2][4096];  // [128][32]
  __shared__ unsigned short sB[2][4096];
  const int tid = threadIdx.x;
  const int lane = tid & 63, w = tid >> 6;

  int flat = blockIdx.y * 4 + blockIdx.x;
  { int c = 2048 >> 3; flat = (flat & 7) * c + (flat >> 3); }
  const int row0 = (flat >> 2) << 7;
  const int col0 = (flat & 3) << 7;
  const int K = 512;

  const int wm = (w >> 1) << 6, wn = (w & 1) << 6;
  const int lrow = lane & 15, kt = (lane >> 4) << 3;
  const int srow = lane >> 2, scol = (lane & 3) << 3;

  f32x4 acc[4][4];
  #pragma unroll
  for (int m = 0; m < 4; ++m)
    #pragma unroll
    for (int n = 0; n < 4; ++n) acc[m][n] = f32x4{0.f, 0.f, 0.f, 0.f};

  auto stage = [&](int buf, int k0) {
    #pragma unroll
    for (int i = 0; i < 2; ++i) {
      int ii = w * 2 + i;
      int r = (ii << 4) + srow;
      GLD16(A + (size_t)(row0 + r) * K + k0 + scol, &sA[buf][ii * 512]);
      GLD16(W + (size_t)(col0 + r) * K + k0 + scol, &sB[buf][ii * 512]);
    }
  };

  stage(0, 0);
  int cur = 0;
  for (int t = 0; t < 16; ++t) {
    __syncthreads();
    if (t + 1 < 16) stage(cur ^ 1, (t + 1) << 5);
    bf16x8 af[4], bfv[4];
    #pragma unroll
    for (int m = 0; m < 4; ++m)
      af[m] = *reinterpret_cast<const bf16x8*>(&sA[cur][(wm + m * 16 + lrow) * 32 + kt]);
    #pragma unroll
    for (int n = 0; n < 4; ++n)
      bfv[n] = *reinterpret_cast<const bf16x8*>(&sB[cur][(wn + n * 16 + lrow) * 32 + kt]);
    #pragma unroll
    for (int m = 0; m < 4; ++m)
      #pragma unroll
      for (int n = 0; n < 4; ++n)
        acc[m][n] = __builtin_amdgcn_mfma_f32_16x16x32_bf16(af[m], bfv[n], acc[m][n], 0, 0, 0);
    cur ^= 1;
  }

  const int rb = (lane >> 4) << 2;  // C/D: col = lane&15, row = (lane>>4)*4 + reg
  const int b = row0 >> 10;
  const int n0 = row0 & 1023;
  unsigned short* vb = vT + ((size_t)b << 19);
  #pragma unroll
  for (int m = 0; m < 4; ++m) {
    #pragma unroll
    for (int n = 0; n < 4; ++n) {
      int col = col0 + wn + n * 16 + lrow;          // d
      int nn = n0 + wm + m * 16 + rb;               // n (4 consecutive)
      ushort4 o;
      o.x = f2bf(acc[m][n][0]); o.y = f2bf(acc[m][n][1]);
      o.z = f2bf(acc[m][n][2]); o.w = f2bf(acc[m][n][3]);
      *reinterpret_cast<ushort4*>(vb + (size_t)col * 1024 + nn) = o;
    }
  }
}

// ---------------- q2[b][16][512] = sn_b @ W'  (B = W'T rows, K=512) ----------------
// grid (4 col-tiles, 64 b), block 256. M=16, N-tile=128.

__global__ __launch_bounds__(256) void q2_k(
    const unsigned short* __restrict__ sn, const unsigned short* __restrict__ wpt,
    unsigned short* __restrict__ q2) {
  __shared__ unsigned short sA[2][512];   // [16][32]
  __shared__ unsigned short sB[2][4096];  // [128][32]
  const int b = blockIdx.y, ct = blockIdx.x;
  const int lane = threadIdx.x & 63, w = threadIdx.x >> 6;
  const int lrow = lane & 15, kt = (lane >> 4) << 3;
  const int srow = lane >> 2, scol = (lane & 3) << 3;
  const unsigned short* Ab = sn + ((size_t)b << 13);
  const unsigned short* Bb = wpt + (size_t)(ct << 7) * 512;

  f32x4 acc[2];
  acc[0] = f32x4{0.f, 0.f, 0.f, 0.f};
  acc[1] = f32x4{0.f, 0.f, 0.f, 0.f};

  auto stage = [&](int buf, int k0) {
    #pragma unroll
    for (int i = 0; i < 2; ++i) {
      int ii = w * 2 + i;
      GLD16(Bb + (size_t)((ii << 4) + srow) * 512 + k0 + scol, &sB[buf][ii * 512]);
    }
    if (w == 0)
      GLD16(Ab + (size_t)srow * 512 + k0 + scol, &sA[buf][0]);
  };

  stage(0, 0);
  int cur = 0;
  for (int t = 0; t < 16; ++t) {
    __syncthreads();
    if (t + 1 < 16) stage(cur ^ 1, (t + 1) << 5);
    bf16x8 af = *reinterpret_cast<const bf16x8*>(&sA[cur][lrow * 32 + kt]);
    #pragma unroll
    for (int ni = 0; ni < 2; ++ni) {
      bf16x8 bfv = *reinterpret_cast<const bf16x8*>(&sB[cur][((w * 2 + ni) * 16 + lrow) * 32 + kt]);
      acc[ni] = __builtin_amdgcn_mfma_f32_16x16x32_bf16(af, bfv, acc[ni], 0, 0, 0);
    }
    cur ^= 1;
  }

  const int rb = (lane >> 4) << 2;
  #pragma unroll
  for (int ni = 0; ni < 2; ++ni) {
    int col = (ct << 7) + (w * 2 + ni) * 16 + lrow;
    #pragma unroll
    for (int r = 0; r < 4; ++r) {
      int s = rb + r;
      q2[(size_t)((b << 4) + s) * 512 + col] = f2bf(acc[ni][r]);
    }
  }
}

// ---------------- logits[b][16][1024] = q2_b @ x_b^T  (f32 out) ----------------
// grid (8 n-tiles, 64 b). M=16, N-tile=128, K=512.

__global__ __launch_bounds__(256) void logits_k(
    const unsigned short* __restrict__ q2, const unsigned short* __restrict__ x,
    float* __restrict__ out) {
  __shared__ unsigned short sA[2][512];   // [16][32]
  __shared__ unsigned short sB[2][4096];  // [128][32]
  const int b = blockIdx.y, nt = blockIdx.x;
  const int lane = threadIdx.x & 63, w = threadIdx.x >> 6;
  const int lrow = lane & 15, kt = (lane >> 4) << 3;
  const int srow = lane >> 2, scol = (lane & 3) << 3;
  const unsigned short* Ab = q2 + ((size_t)b << 13);
  const unsigned short* Bb = x + (((size_t)(b << 10) + (nt << 7)) << 9);

  f32x4 acc[2];
  acc[0] = f32x4{0.f, 0.f, 0.f, 0.f};
  acc[1] = f32x4{0.f, 0.f, 0.f, 0.f};

  auto stage = [&](int buf, int k0) {
    #pragma unroll
    for (int i = 0; i < 2; ++i) {
      int ii = w * 2 + i;
      GLD16(Bb + (size_t)((ii << 4) + srow) * 512 + k0 + scol, &sB[buf][ii * 512]);
    }
    if (w == 0)
      GLD16(Ab + (size_t)srow * 512 + k0 + scol, &sA[buf][0]);
  };

  stage(0, 0);
  int cur = 0;
  for (int t = 0; t < 16; ++t) {
    __syncthreads();
    if (t + 1 < 16) stage(cur ^ 1, (t + 1) << 5);
    bf16x8 af = *reinterpret_cast<const bf16x8*>(&sA[cur][lrow * 32 + kt]);
    #pragma unroll
    for (int ni = 0; ni < 2; ++ni) {
      bf16x8 bfv = *reinterpret_cast<const bf16x8*>(&sB[cur][((w * 2 + ni) * 16 + lrow) * 32 + kt]);
      acc[ni] = __builtin_amdgcn_mfma_f32_16x16x32_bf16(af, bfv, acc[ni], 0, 0, 0);
    }
    cur ^= 1;
  }

  const int rb = (lane >> 4) << 2;
  #pragma unroll
  for (int ni = 0; ni < 2; ++ni) {
    int n = (nt << 7) + (w * 2 + ni) * 16 + lrow;
    #pragma unroll
    for (int r = 0; r < 4; ++r) {
      int s = rb + r;
      out[(size_t)((b << 4) + s) * 1024 + n] = acc[ni][r];
    }
  }
}

// ---------------- softmax over n, column-normalize over s; bf16 out ----------------

__global__ __launch_bounds__(1024) void softmax_cn_k(
    const float* __restrict__ logits, unsigned short* __restrict__ attn) {
  __shared__ float sp[16][1024];
  int b = blockIdx.x;
  int w = threadIdx.x >> 6, lane = threadIdx.x & 63;
  const float* rp = logits + ((size_t)b * 16 + w) * 1024;
  float v[16];
  float mx = -3.4e38f;
  #pragma unroll
  for (int i = 0; i < 16; ++i) { v[i] = rp[lane + (i << 6)]; mx = fmaxf(mx, v[i]); }
  #pragma unroll
  for (int o = 32; o > 0; o >>= 1) mx = fmaxf(mx, __shfl_xor(mx, o));
  float s = 0.f;
  #pragma unroll
  for (int i = 0; i < 16; ++i) { v[i] = __expf(v[i] - mx); s += v[i]; }
  #pragma unroll
  for (int o = 32; o > 0; o >>= 1) s += __shfl_xor(s, o);
  float inv = 1.0f / s;
  #pragma unroll
  for (int i = 0; i < 16; ++i) sp[w][lane + (i << 6)] = v[i] * inv;
  __syncthreads();
  int col = threadIdx.x;
  float cs = 0.f;
  #pragma unroll
  for (int s2 = 0; s2 < 16; ++s2) cs += sp[s2][col];
  float rinv = 1.0f / (cs + 1e-8f);
  unsigned short* ob = attn + ((size_t)b << 14);
  #pragma unroll
  for (int s2 = 0; s2 < 16; ++s2) ob[s2 * 1024 + col] = f2bf(sp[s2][col] * rinv);
}

// ---------------- pv: upd^T[d][s] = vT_b @ attn_b^T -> A2 left half ----------------
// grid (4 d-tiles, 64 b). M-tile=128 (d), N=16 (s), K=1024 (n).

__global__ __launch_bounds__(256) void pv_k(
    const unsigned short* __restrict__ vT, const unsigned short* __restrict__ attn,
    unsigned short* __restrict__ A2) {
  __shared__ unsigned short sA[2][4096];  // [128 d][32 n]
  __shared__ unsigned short sB[2][512];   // [16 s][32 n]
  const int b = blockIdx.y, dt = blockIdx.x;
  const int lane = threadIdx.x & 63, w = threadIdx.x >> 6;
  const int lrow = lane & 15, kt = (lane >> 4) << 3;
  const int srow = lane >> 2, scol = (lane & 3) << 3;
  const unsigned short* Ab = vT + ((size_t)b << 19) + (size_t)(dt << 7) * 1024;
  const unsigned short* Bb = attn + ((size_t)b << 14);

  f32x4 acc[2];
  acc[0] = f32x4{0.f, 0.f, 0.f, 0.f};
  acc[1] = f32x4{0.f, 0.f, 0.f, 0.f};

  auto stage = [&](int buf, int k0) {
    #pragma unroll
    for (int i = 0; i < 2; ++i) {
      int ii = w * 2 + i;
      GLD16(Ab + (size_t)((ii << 4) + srow) * 1024 + k0 + scol, &sA[buf][ii * 512]);
    }
    if (w == 0)
      GLD16(Bb + (size_t)srow * 1024 + k0 + scol, &sB[buf][0]);
  };

  stage(0, 0);
  int cur = 0;
  for (int t = 0; t < 32; ++t) {
    __syncthreads();
    if (t + 1 < 32) stage(cur ^ 1, (t + 1) << 5);
    bf16x8 bfv = *reinterpret_cast<const bf16x8*>(&sB[cur][lrow * 32 + kt]);
    #pragma unroll
    for (int mi = 0; mi < 2; ++mi) {
      bf16x8 af = *reinterpret_cast<const bf16x8*>(&sA[cur][((w * 2 + mi) * 16 + lrow) * 32 + kt]);
      acc[mi] = __builtin_amdgcn_mfma_f32_16x16x32_bf16(af, bfv, acc[mi], 0, 0, 0);
    }
    cur ^= 1;
  }

  const int rb = (lane >> 4) << 2;
  const int s = lrow;  // C col = lane&15
  #pragma unroll
  for (int mi = 0; mi < 2; ++mi) {
    int d0 = (dt << 7) + (w * 2 + mi) * 16 + rb;  // C rows (4 consecutive d)
    ushort4 o;
    o.x = f2bf(acc[mi][0]); o.y = f2bf(acc[mi][1]);
    o.z = f2bf(acc[mi][2]); o.w = f2bf(acc[mi][3]);
    *reinterpret_cast<ushort4*>(&A2[(size_t)((b << 4) + s) * 1024 + d0]) = o;
  }
}

// ---------------- MFMA GEMM 64x64 (slot-sized GEMMs) ----------------

template<int BIAS, int RELU, int ADDSRC, int OUTBF16>
__global__ __launch_bounds__(256) void gemm_sm(
    const unsigned short* __restrict__ A, const unsigned short* __restrict__ W,
    const float* __restrict__ bias, const float* __restrict__ addsrc,
    void* __restrict__ Cout, int M, int N, int K) {
  __shared__ unsigned short sA[2][2048];  // [64][32]
  __shared__ unsigned short sB[2][2048];
  const int tid = threadIdx.x;
  const int lane = tid & 63, w = tid >> 6;

  int nwg = gridDim.x * gridDim.y;
  int flat = blockIdx.y * gridDim.x + blockIdx.x;
  if ((nwg & 7) == 0) { int c = nwg >> 3; flat = (flat & 7) * c + (flat >> 3); }
  const int row0 = (flat / gridDim.x) << 6;
  const int col0 = (flat % gridDim.x) << 6;

  const int lrow = lane & 15, kt = (lane >> 4) << 3;
  const int srow = lane >> 2, scol = (lane & 3) << 3;

  f32x4 acc[4];
  #pragma unroll
  for (int m = 0; m < 4; ++m) acc[m] = f32x4{0.f, 0.f, 0.f, 0.f};

  auto stage = [&](int buf, int k0) {
    int r = (w << 4) + srow;
    GLD16(A + (size_t)(row0 + r) * K + k0 + scol, &sA[buf][w * 512]);
    GLD16(W + (size_t)(col0 + r) * K + k0 + scol, &sB[buf][w * 512]);
  };

  stage(0, 0);
  const int nt = K >> 5;
  int cur = 0;
  for (int t = 0; t < nt; ++t) {
    __syncthreads();
    if (t + 1 < nt) stage(cur ^ 1, (t + 1) << 5);
    bf16x8 af[4], bfv;
    #pragma unroll
    for (int m = 0; m < 4; ++m)
      af[m] = *reinterpret_cast<const bf16x8*>(&sA[cur][(m * 16 + lrow) * 32 + kt]);
    bfv = *reinterpret_cast<const bf16x8*>(&sB[cur][((w << 4) + lrow) * 32 + kt]);
    #pragma unroll
    for (int m = 0; m < 4; ++m)
      acc[m] = __builtin_amdgcn_mfma_f32_16x16x32_bf16(af[m], bfv, acc[m], 0, 0, 0);
    cur ^= 1;
  }

  const int rb = (lane >> 4) << 2;
  const int col = col0 + (w << 4) + lrow;
  float bv = BIAS ? bias[col] : 0.0f;
  #pragma unroll
  for (int m = 0; m < 4; ++m) {
    #pragma unroll
    for (int r = 0; r < 4; ++r) {
      int row = row0 + m * 16 + rb + r;
      float v = acc[m][r] + bv;
      if (ADDSRC) v += addsrc[(size_t)row * N + col];
      if (RELU) v = fmaxf(v, 0.0f);
      if (OUTBF16) ((unsigned short*)Cout)[(size_t)row * N + col] = f2bf(v);
      else ((float*)Cout)[(size_t)row * N + col] = v;
    }
  }
}

// ---------------- host launch ----------------

extern "C" void kernel_launch(void* const* d_in, const int* in_sizes, int n_in,
                              void* d_out, int out_size, void* d_ws, size_t ws_size,
                              hipStream_t stream) {
  const float* inputs  = (const float*)d_in[0];
  const float* noise   = (const float*)d_in[1];
  const float* slot_mu = (const float*)d_in[2];
  const float* slot_ls = (const float*)d_in[3];
  const float* ln_in_g = (const float*)d_in[4];
  const float* ln_in_b = (const float*)d_in[5];
  const float* ln_s_g  = (const float*)d_in[6];
  const float* ln_s_b  = (const float*)d_in[7];
  const float* ln_m_g  = (const float*)d_in[8];
  const float* ln_m_b  = (const float*)d_in[9];
  const float* Wq   = (const float*)d_in[10];
  const float* Wk   = (const float*)d_in[11];
  const float* Wv   = (const float*)d_in[12];
  const float* w_ih = (const float*)d_in[13];
  const float* w_hh = (const float*)d_in[14];
  const float* b_ih = (const float*)d_in[15];
  const float* b_hh = (const float*)d_in[16];
  const float* w1   = (const float*)d_in[17];
  const float* b1   = (const float*)d_in[18];
  const float* w2   = (const float*)d_in[19];
  const float* b2   = (const float*)d_in[20];

  const int BN = 65536, BS = 1024;

  uintptr_t base = (uintptr_t)d_ws;
  auto alloc = [&](size_t bytes) {
    void* p = (void*)base;
    base += (bytes + 255) & ~(size_t)255;
    return p;
  };
  unsigned short* x_bf    = (unsigned short*)alloc((size_t)BN * 512 * 2);
  unsigned short* vT      = (unsigned short*)alloc((size_t)64 * 512 * 1024 * 2);
  unsigned short* wpt     = (unsigned short*)alloc(512 * 512 * 2);
  unsigned short* wv_bf   = (unsigned short*)alloc(512 * 512 * 2);
  unsigned short* wcat_bf = (unsigned short*)alloc((size_t)2048 * 1024 * 2);
  float*          bcat    = (float*)alloc(2048 * 4);
  unsigned short* w1_bf   = (unsigned short*)alloc(512 * 512 * 2);
  unsigned short* w2_bf   = (unsigned short*)alloc(512 * 512 * 2);
  float*          slots   = (float*)alloc((size_t)BS * 512 * 4);
  unsigned short* sn_bf   = (unsigned short*)alloc((size_t)BS * 512 * 2);
  unsigned short* A2      = (unsigned short*)alloc((size_t)BS * 1024 * 2);
  unsigned short* q2_bf   = (unsigned short*)alloc((size_t)BS * 512 * 2);
  float*          logits  = (float*)alloc((size_t)64 * 16 * 1024 * 4);
  unsigned short* attn_bf = (unsigned short*)alloc((size_t)64 * 16 * 1024 * 2);
  float*          gates   = (float*)alloc((size_t)BS * 2048 * 4);
  float*          sgru    = (float*)alloc((size_t)BS * 512 * 4);
  unsigned short* lnm_bf  = (unsigned short*)alloc((size_t)BS * 512 * 2);
  unsigned short* h_bf    = (unsigned short*)alloc((size_t)BS * 512 * 2);
  (void)ws_size; (void)n_in; (void)in_sizes; (void)out_size;

  // weight prep
  wcomp_k<<<dim3(2, 64), 256, 0, stream>>>(Wq, Wk, wpt);
  cast_bf16_k<<<1024, 256, 0, stream>>>(Wv, wv_bf, 262144);
  wcat_k<<<8192, 256, 0, stream>>>(w_ih, w_hh, wcat_bf);
  bcat_k<<<8, 256, 0, stream>>>(b_ih, b_hh, bcat);
  cast_bf16_k<<<1024, 256, 0, stream>>>(w1, w1_bf, 262144);
  cast_bf16_k<<<1024, 256, 0, stream>>>(w2, w2_bf, 262144);

  init_slots_k<<<2048, 256, 0, stream>>>(slot_mu, slot_ls, noise, slots);
  ln_rows_k<<<16384, 256, 0, stream>>>(inputs, ln_in_g, ln_in_b, x_bf, BN);
  gemm_vt<<<dim3(4, 512), 256, 0, stream>>>(x_bf, wv_bf, vT);

  for (int it = 0; it < 3; ++it) {
    ln_cast_k<<<256, 256, 0, stream>>>(slots, ln_s_g, ln_s_b, sn_bf, A2);
    q2_k<<<dim3(4, 64), 256, 0, stream>>>(sn_bf, wpt, q2_bf);
    logits_k<<<dim3(8, 64), 256, 0, stream>>>(q2_bf, x_bf, logits);
    softmax_cn_k<<<64, 1024, 0, stream>>>(logits, attn_bf);
    pv_k<<<dim3(4, 64), 256, 0, stream>>>(vT, attn_bf, A2);
    gemm_sm<1,0,0,0><<<dim3(32, 16), 256, 0, stream>>>(
        A2, wcat_bf, bcat, nullptr, gates, BS, 2048, 1024);
    gru_ln_k<<<256, 256, 0, stream>>>(gates, slots, ln_m_g, ln_m_b, sgru, lnm_bf);
    gemm_sm<1,1,0,1><<<dim3(8, 16), 256, 0, stream>>>(
        lnm_bf, w1_bf, b1, nullptr, h_bf, BS, 512, 512);
    float* slots_out = (it == 2) ? (float*)d_out : slots;
    gemm_sm<1,0,1,0><<<dim3(8, 16), 256, 0, stream>>>(
        h_bf, w2_bf, b2, sgru, slots_out, BS, 512, 512);
  }
}

// Round 6
// 365.940 us; speedup vs baseline: 2.2008x; 1.2597x over previous
//
#include <hip/hip_runtime.h>
#include <hip/hip_bf16.h>
#include <cstdint>
#include <cstddef>

// Shapes fixed: B=64, N=1024, D=512, S=16, 3 iterations.
// Algebra: logits = sn·W'·x^T with W' = scale·Wq^T·Wk  (k never materialized)
//          updates^T = vT_b @ attn_b^T  (vT stored transposed per batch)

typedef __bf16 bf16x8 __attribute__((ext_vector_type(8)));
typedef float f32x4 __attribute__((ext_vector_type(4)));

__device__ __forceinline__ float bf2f(unsigned int u) {
  union { unsigned int i; float f; } v; v.i = u << 16; return v.f;
}
__device__ __forceinline__ unsigned short f2bf(float x) {
  __hip_bfloat16 h = __float2bfloat16(x);
  unsigned short u;
  __builtin_memcpy(&u, &h, 2);
  return u;
}

#define GLD16(gp, lp)                                                       \
  __builtin_amdgcn_global_load_lds(                                         \
      (const __attribute__((address_space(1))) void*)(gp),                  \
      (__attribute__((address_space(3))) void*)(lp), 16, 0, 0)

// ---------------- elementwise / weight prep ----------------

__global__ void cast_bf16_k(const float* __restrict__ in, unsigned short* __restrict__ out, int n) {
  int i = blockIdx.x * 256 + threadIdx.x;
  if (i < n) out[i] = f2bf(in[i]);
}

// transpose + cast: out[c][r] = bf16(in[r][c]), 512x512, grid (16,16), block 256
__global__ __launch_bounds__(256) void tcast_k(const float* __restrict__ in,
                                               unsigned short* __restrict__ out) {
  __shared__ float t[32][33];
  int c0 = blockIdx.x << 5, r0 = blockIdx.y << 5;
  int tx = threadIdx.x & 31, ty = threadIdx.x >> 5;
  #pragma unroll
  for (int i = 0; i < 4; ++i)
    t[ty + 8 * i][tx] = in[(size_t)(r0 + ty + 8 * i) * 512 + c0 + tx];
  __syncthreads();
  #pragma unroll
  for (int i = 0; i < 4; ++i)
    out[(size_t)(c0 + ty + 8 * i) * 512 + r0 + tx] = f2bf(t[tx][ty + 8 * i]);
}

__global__ void init_slots_k(const float* __restrict__ mu, const float* __restrict__ ls,
                             const float* __restrict__ noise, float* __restrict__ slots) {
  int i = blockIdx.x * 256 + threadIdx.x;
  int d = i & 511;
  slots[i] = mu[d] + expf(ls[d]) * noise[i];
}

// Wcat [2048][1024]: rows j<1024: [wih[j] | whh[j]]; [1024,1536): [wih[j] | 0];
// [1536,2048): [0 | whh[j-512]]
__global__ void wcat_k(const float* __restrict__ wih, const float* __restrict__ whh,
                       unsigned short* __restrict__ out) {
  int i = blockIdx.x * 256 + threadIdx.x;  // 2M total
  int j = i >> 10, k = i & 1023;
  float v;
  if (j < 1024)      v = (k < 512) ? wih[j * 512 + k] : whh[j * 512 + (k - 512)];
  else if (j < 1536) v = (k < 512) ? wih[j * 512 + k] : 0.0f;
  else               v = (k < 512) ? 0.0f : whh[(j - 512) * 512 + (k - 512)];
  out[i] = f2bf(v);
}

__global__ void bcat_k(const float* __restrict__ bih, const float* __restrict__ bhh,
                       float* __restrict__ out) {
  int j = blockIdx.x * 256 + threadIdx.x;  // 2048
  float v;
  if (j < 1024)      v = bih[j] + bhh[j];
  else if (j < 1536) v = bih[j];
  else               v = bhh[j - 512];
  out[j] = v;
}

// ---------------- layernorm (wave per row, D=512) ----------------

__global__ __launch_bounds__(256) void ln_rows_k(
    const float* __restrict__ in, const float* __restrict__ g, const float* __restrict__ b,
    unsigned short* __restrict__ out, int rows) {
  int w = threadIdx.x >> 6, lane = threadIdx.x & 63;
  int row = (blockIdx.x << 2) + w;
  if (row >= rows) return;
  const float4* rp = reinterpret_cast<const float4*>(in + (size_t)row * 512);
  float4 v0 = rp[lane], v1 = rp[lane + 64];
  float s = v0.x + v0.y + v0.z + v0.w + v1.x + v1.y + v1.z + v1.w;
  float q = v0.x*v0.x + v0.y*v0.y + v0.z*v0.z + v0.w*v0.w
          + v1.x*v1.x + v1.y*v1.y + v1.z*v1.z + v1.w*v1.w;
  #pragma unroll
  for (int o = 32; o > 0; o >>= 1) { s += __shfl_xor(s, o); q += __shfl_xor(q, o); }
  float m = s * (1.0f / 512.0f);
  float rstd = rsqrtf(q * (1.0f / 512.0f) - m * m + 1e-8f);
  const float4* gp = reinterpret_cast<const float4*>(g);
  const float4* bp = reinterpret_cast<const float4*>(b);
  float4 g0 = gp[lane], g1 = gp[lane + 64];
  float4 b0 = bp[lane], b1 = bp[lane + 64];
  ushort4 o0, o1;
  o0.x = f2bf((v0.x - m) * rstd * g0.x + b0.x);
  o0.y = f2bf((v0.y - m) * rstd * g0.y + b0.y);
  o0.z = f2bf((v0.z - m) * rstd * g0.z + b0.z);
  o0.w = f2bf((v0.w - m) * rstd * g0.w + b0.w);
  o1.x = f2bf((v1.x - m) * rstd * g1.x + b1.x);
  o1.y = f2bf((v1.y - m) * rstd * g1.y + b1.y);
  o1.z = f2bf((v1.z - m) * rstd * g1.z + b1.z);
  o1.w = f2bf((v1.w - m) * rstd * g1.w + b1.w);
  ushort4* op = reinterpret_cast<ushort4*>(out + (size_t)row * 512);
  op[lane] = o0; op[lane + 64] = o1;
}

// LN(slots)->sn_bf AND raw cast slots -> A2 right half (row stride 1024)
__global__ __launch_bounds__(256) void ln_cast_k(
    const float* __restrict__ in, const float* __restrict__ g, const float* __restrict__ b,
    unsigned short* __restrict__ sn, unsigned short* __restrict__ A2) {
  int w = threadIdx.x >> 6, lane = threadIdx.x & 63;
  int row = (blockIdx.x << 2) + w;
  const float4* rp = reinterpret_cast<const float4*>(in + (size_t)row * 512);
  float4 v0 = rp[lane], v1 = rp[lane + 64];
  float s = v0.x + v0.y + v0.z + v0.w + v1.x + v1.y + v1.z + v1.w;
  float q = v0.x*v0.x + v0.y*v0.y + v0.z*v0.z + v0.w*v0.w
          + v1.x*v1.x + v1.y*v1.y + v1.z*v1.z + v1.w*v1.w;
  #pragma unroll
  for (int o = 32; o > 0; o >>= 1) { s += __shfl_xor(s, o); q += __shfl_xor(q, o); }
  float m = s * (1.0f / 512.0f);
  float rstd = rsqrtf(q * (1.0f / 512.0f) - m * m + 1e-8f);
  const float4* gp = reinterpret_cast<const float4*>(g);
  const float4* bp = reinterpret_cast<const float4*>(b);
  float4 g0 = gp[lane], g1 = gp[lane + 64];
  float4 b0 = bp[lane], b1 = bp[lane + 64];
  ushort4 c0, c1, o0, o1;
  c0.x = f2bf(v0.x); c0.y = f2bf(v0.y); c0.z = f2bf(v0.z); c0.w = f2bf(v0.w);
  c1.x = f2bf(v1.x); c1.y = f2bf(v1.y); c1.z = f2bf(v1.z); c1.w = f2bf(v1.w);
  o0.x = f2bf((v0.x - m) * rstd * g0.x + b0.x);
  o0.y = f2bf((v0.y - m) * rstd * g0.y + b0.y);
  o0.z = f2bf((v0.z - m) * rstd * g0.z + b0.z);
  o0.w = f2bf((v0.w - m) * rstd * g0.w + b0.w);
  o1.x = f2bf((v1.x - m) * rstd * g1.x + b1.x);
  o1.y = f2bf((v1.y - m) * rstd * g1.y + b1.y);
  o1.z = f2bf((v1.z - m) * rstd * g1.z + b1.z);
  o1.w = f2bf((v1.w - m) * rstd * g1.w + b1.w);
  ushort4* sp_ = reinterpret_cast<ushort4*>(sn + (size_t)row * 512);
  ushort4* cp_ = reinterpret_cast<ushort4*>(A2 + (size_t)row * 1024 + 512);
  sp_[lane] = o0; sp_[lane + 64] = o1;
  cp_[lane] = c0; cp_[lane + 64] = c1;
}

// GRU (fused-gates layout) + LN: gates[row][2048] = [rsum, zsum, i_n, h_n]
__global__ __launch_bounds__(256) void gru_ln_k(
    const float* __restrict__ gates, const float* __restrict__ hp,
    const float* __restrict__ g, const float* __restrict__ b,
    float* __restrict__ sgru, unsigned short* __restrict__ lnm) {
  int w = threadIdx.x >> 6, lane = threadIdx.x & 63;
  int row = (blockIdx.x << 2) + w;
  size_t gb = (size_t)row * 2048 + (lane << 3);
  size_t hb = (size_t)row * 512 + (lane << 3);
  float rs[8], zs[8], in_[8], hn[8], hv[8], y[8];
  #pragma unroll
  for (int c = 0; c < 2; ++c) {
    *reinterpret_cast<float4*>(rs + 4*c)  = *reinterpret_cast<const float4*>(gates + gb + 4*c);
    *reinterpret_cast<float4*>(zs + 4*c)  = *reinterpret_cast<const float4*>(gates + gb + 512 + 4*c);
    *reinterpret_cast<float4*>(in_ + 4*c) = *reinterpret_cast<const float4*>(gates + gb + 1024 + 4*c);
    *reinterpret_cast<float4*>(hn + 4*c)  = *reinterpret_cast<const float4*>(gates + gb + 1536 + 4*c);
    *reinterpret_cast<float4*>(hv + 4*c)  = *reinterpret_cast<const float4*>(hp + hb + 4*c);
  }
  float s = 0.f, q = 0.f;
  #pragma unroll
  for (int j = 0; j < 8; ++j) {
    float r = 1.0f / (1.0f + expf(-rs[j]));
    float z = 1.0f / (1.0f + expf(-zs[j]));
    float n = tanhf(in_[j] + r * hn[j]);
    float h = (1.0f - z) * n + z * hv[j];
    y[j] = h; s += h; q += h * h;
  }
  #pragma unroll
  for (int o = 32; o > 0; o >>= 1) { s += __shfl_xor(s, o); q += __shfl_xor(q, o); }
  float m = s * (1.0f / 512.0f);
  float rstd = rsqrtf(q * (1.0f / 512.0f) - m * m + 1e-8f);
  const float* gg = g + (lane << 3);
  const float* bb = b + (lane << 3);
  #pragma unroll
  for (int c = 0; c < 2; ++c)
    *reinterpret_cast<float4*>(sgru + hb + 4*c) = *reinterpret_cast<const float4*>(y + 4*c);
  uint4 o4;
  unsigned int p[8];
  #pragma unroll
  for (int j = 0; j < 8; ++j) p[j] = f2bf((y[j] - m) * rstd * gg[j] + bb[j]);
  o4.x = p[0] | (p[1] << 16); o4.y = p[2] | (p[3] << 16);
  o4.z = p[4] | (p[5] << 16); o4.w = p[6] | (p[7] << 16);
  *reinterpret_cast<uint4*>(lnm + hb) = o4;
}

// ---------------- gemm_vt: vT[b][d][n] = (x @ Wv^T) transposed per b ----------------
// A = x [65536][512], W = wv [512][512]. 128x128 tile, grid (4, 512).

__global__ __launch_bounds__(256) void gemm_vt(
    const unsigned short* __restrict__ A, const unsigned short* __restrict__ W,
    unsigned short* __restrict__ vT) {
  __shared__ unsigned short sA[2][4096];  // [128][32]
  __shared__ unsigned short sB[2][4096];
  const int tid = threadIdx.x;
  const int lane = tid & 63, w = tid >> 6;

  int flat = blockIdx.y * 4 + blockIdx.x;
  { int c = 2048 >> 3; flat = (flat & 7) * c + (flat >> 3); }
  const int row0 = (flat >> 2) << 7;
  const int col0 = (flat & 3) << 7;
  const int K = 512;

  const int wm = (w >> 1) << 6, wn = (w & 1) << 6;
  const int lrow = lane & 15, kt = (lane >> 4) << 3;
  const int srow = lane >> 2, scol = (lane & 3) << 3;

  f32x4 acc[4][4];
  #pragma unroll
  for (int m = 0; m < 4; ++m)
    #pragma unroll
    for (int n = 0; n < 4; ++n) acc[m][n] = f32x4{0.f, 0.f, 0.f, 0.f};

  auto stage = [&](int buf, int k0) {
    #pragma unroll
    for (int i = 0; i < 2; ++i) {
      int ii = w * 2 + i;
      int r = (ii << 4) + srow;
      GLD16(A + (size_t)(row0 + r) * K + k0 + scol, &sA[buf][ii * 512]);
      GLD16(W + (size_t)(col0 + r) * K + k0 + scol, &sB[buf][ii * 512]);
    }
  };

  stage(0, 0);
  int cur = 0;
  for (int t = 0; t < 16; ++t) {
    __syncthreads();
    if (t + 1 < 16) stage(cur ^ 1, (t + 1) << 5);
    bf16x8 af[4], bfv[4];
    #pragma unroll
    for (int m = 0; m < 4; ++m)
      af[m] = *reinterpret_cast<const bf16x8*>(&sA[cur][(wm + m * 16 + lrow) * 32 + kt]);
    #pragma unroll
    for (int n = 0; n < 4; ++n)
      bfv[n] = *reinterpret_cast<const bf16x8*>(&sB[cur][(wn + n * 16 + lrow) * 32 + kt]);
    #pragma unroll
    for (int m = 0; m < 4; ++m)
      #pragma unroll
      for (int n = 0; n < 4; ++n)
        acc[m][n] = __builtin_amdgcn_mfma_f32_16x16x32_bf16(af[m], bfv[n], acc[m][n], 0, 0, 0);
    cur ^= 1;
  }

  const int rb = (lane >> 4) << 2;  // C/D: col = lane&15, row = (lane>>4)*4 + reg
  const int b = row0 >> 10;
  const int n0 = row0 & 1023;
  unsigned short* vb = vT + ((size_t)b << 19);
  #pragma unroll
  for (int m = 0; m < 4; ++m) {
    #pragma unroll
    for (int n = 0; n < 4; ++n) {
      int col = col0 + wn + n * 16 + lrow;          // d
      int nn = n0 + wm + m * 16 + rb;               // n (4 consecutive)
      ushort4 o;
      o.x = f2bf(acc[m][n][0]); o.y = f2bf(acc[m][n][1]);
      o.z = f2bf(acc[m][n][2]); o.w = f2bf(acc[m][n][3]);
      *reinterpret_cast<ushort4*>(vb + (size_t)col * 1024 + nn) = o;
    }
  }
}

// ---------------- q2[b][16][512] = sn_b @ W'  (B = W'T rows, K=512) ----------------
// grid (4 col-tiles, 64 b), block 256. M=16, N-tile=128.

__global__ __launch_bounds__(256) void q2_k(
    const unsigned short* __restrict__ sn, const unsigned short* __restrict__ wpt,
    unsigned short* __restrict__ q2) {
  __shared__ unsigned short sA[2][512];   // [16][32]
  __shared__ unsigned short sB[2][4096];  // [128][32]
  const int b = blockIdx.y, ct = blockIdx.x;
  const int lane = threadIdx.x & 63, w = threadIdx.x >> 6;
  const int lrow = lane & 15, kt = (lane >> 4) << 3;
  const int srow = lane >> 2, scol = (lane & 3) << 3;
  const unsigned short* Ab = sn + ((size_t)b << 13);
  const unsigned short* Bb = wpt + (size_t)(ct << 7) * 512;

  f32x4 acc[2];
  acc[0] = f32x4{0.f, 0.f, 0.f, 0.f};
  acc[1] = f32x4{0.f, 0.f, 0.f, 0.f};

  auto stage = [&](int buf, int k0) {
    #pragma unroll
    for (int i = 0; i < 2; ++i) {
      int ii = w * 2 + i;
      GLD16(Bb + (size_t)((ii << 4) + srow) * 512 + k0 + scol, &sB[buf][ii * 512]);
    }
    if (w == 0)
      GLD16(Ab + (size_t)srow * 512 + k0 + scol, &sA[buf][0]);
  };

  stage(0, 0);
  int cur = 0;
  for (int t = 0; t < 16; ++t) {
    __syncthreads();
    if (t + 1 < 16) stage(cur ^ 1, (t + 1) << 5);
    bf16x8 af = *reinterpret_cast<const bf16x8*>(&sA[cur][lrow * 32 + kt]);
    #pragma unroll
    for (int ni = 0; ni < 2; ++ni) {
      bf16x8 bfv = *reinterpret_cast<const bf16x8*>(&sB[cur][((w * 2 + ni) * 16 + lrow) * 32 + kt]);
      acc[ni] = __builtin_amdgcn_mfma_f32_16x16x32_bf16(af, bfv, acc[ni], 0, 0, 0);
    }
    cur ^= 1;
  }

  const int rb = (lane >> 4) << 2;
  #pragma unroll
  for (int ni = 0; ni < 2; ++ni) {
    int col = (ct << 7) + (w * 2 + ni) * 16 + lrow;
    #pragma unroll
    for (int r = 0; r < 4; ++r) {
      int s = rb + r;
      q2[(size_t)((b << 4) + s) * 512 + col] = f2bf(acc[ni][r]);
    }
  }
}

// ---------------- logits[b][16][1024] = q2_b @ x_b^T  (f32 out) ----------------
// grid (8 n-tiles, 64 b). M=16, N-tile=128, K=512.

__global__ __launch_bounds__(256) void logits_k(
    const unsigned short* __restrict__ q2, const unsigned short* __restrict__ x,
    float* __restrict__ out) {
  __shared__ unsigned short sA[2][512];   // [16][32]
  __shared__ unsigned short sB[2][4096];  // [128][32]
  const int b = blockIdx.y, nt = blockIdx.x;
  const int lane = threadIdx.x & 63, w = threadIdx.x >> 6;
  const int lrow = lane & 15, kt = (lane >> 4) << 3;
  const int srow = lane >> 2, scol = (lane & 3) << 3;
  const unsigned short* Ab = q2 + ((size_t)b << 13);
  const unsigned short* Bb = x + (((size_t)(b << 10) + (nt << 7)) << 9);

  f32x4 acc[2];
  acc[0] = f32x4{0.f, 0.f, 0.f, 0.f};
  acc[1] = f32x4{0.f, 0.f, 0.f, 0.f};

  auto stage = [&](int buf, int k0) {
    #pragma unroll
    for (int i = 0; i < 2; ++i) {
      int ii = w * 2 + i;
      GLD16(Bb + (size_t)((ii << 4) + srow) * 512 + k0 + scol, &sB[buf][ii * 512]);
    }
    if (w == 0)
      GLD16(Ab + (size_t)srow * 512 + k0 + scol, &sA[buf][0]);
  };

  stage(0, 0);
  int cur = 0;
  for (int t = 0; t < 16; ++t) {
    __syncthreads();
    if (t + 1 < 16) stage(cur ^ 1, (t + 1) << 5);
    bf16x8 af = *reinterpret_cast<const bf16x8*>(&sA[cur][lrow * 32 + kt]);
    #pragma unroll
    for (int ni = 0; ni < 2; ++ni) {
      bf16x8 bfv = *reinterpret_cast<const bf16x8*>(&sB[cur][((w * 2 + ni) * 16 + lrow) * 32 + kt]);
      acc[ni] = __builtin_amdgcn_mfma_f32_16x16x32_bf16(af, bfv, acc[ni], 0, 0, 0);
    }
    cur ^= 1;
  }

  const int rb = (lane >> 4) << 2;
  #pragma unroll
  for (int ni = 0; ni < 2; ++ni) {
    int n = (nt << 7) + (w * 2 + ni) * 16 + lrow;
    #pragma unroll
    for (int r = 0; r < 4; ++r) {
      int s = rb + r;
      out[(size_t)((b << 4) + s) * 1024 + n] = acc[ni][r];
    }
  }
}

// ---------------- softmax over n, column-normalize over s; bf16 out ----------------

__global__ __launch_bounds__(1024) void softmax_cn_k(
    const float* __restrict__ logits, unsigned short* __restrict__ attn) {
  __shared__ float sp[16][1024];
  int b = blockIdx.x;
  int w = threadIdx.x >> 6, lane = threadIdx.x & 63;
  const float* rp = logits + ((size_t)b * 16 + w) * 1024;
  float v[16];
  float mx = -3.4e38f;
  #pragma unroll
  for (int i = 0; i < 16; ++i) { v[i] = rp[lane + (i << 6)]; mx = fmaxf(mx, v[i]); }
  #pragma unroll
  for (int o = 32; o > 0; o >>= 1) mx = fmaxf(mx, __shfl_xor(mx, o));
  float s = 0.f;
  #pragma unroll
  for (int i = 0; i < 16; ++i) { v[i] = __expf(v[i] - mx); s += v[i]; }
  #pragma unroll
  for (int o = 32; o > 0; o >>= 1) s += __shfl_xor(s, o);
  float inv = 1.0f / s;
  #pragma unroll
  for (int i = 0; i < 16; ++i) sp[w][lane + (i << 6)] = v[i] * inv;
  __syncthreads();
  int col = threadIdx.x;
  float cs = 0.f;
  #pragma unroll
  for (int s2 = 0; s2 < 16; ++s2) cs += sp[s2][col];
  float rinv = 1.0f / (cs + 1e-8f);
  unsigned short* ob = attn + ((size_t)b << 14);
  #pragma unroll
  for (int s2 = 0; s2 < 16; ++s2) ob[s2 * 1024 + col] = f2bf(sp[s2][col] * rinv);
}

// ---------------- pv: upd^T[d][s] = vT_b @ attn_b^T -> A2 left half ----------------
// grid (4 d-tiles, 64 b). M-tile=128 (d), N=16 (s), K=1024 (n).

__global__ __launch_bounds__(256) void pv_k(
    const unsigned short* __restrict__ vT, const unsigned short* __restrict__ attn,
    unsigned short* __restrict__ A2) {
  __shared__ unsigned short sA[2][4096];  // [128 d][32 n]
  __shared__ unsigned short sB[2][512];   // [16 s][32 n]
  const int b = blockIdx.y, dt = blockIdx.x;
  const int lane = threadIdx.x & 63, w = threadIdx.x >> 6;
  const int lrow = lane & 15, kt = (lane >> 4) << 3;
  const int srow = lane >> 2, scol = (lane & 3) << 3;
  const unsigned short* Ab = vT + ((size_t)b << 19) + (size_t)(dt << 7) * 1024;
  const unsigned short* Bb = attn + ((size_t)b << 14);

  f32x4 acc[2];
  acc[0] = f32x4{0.f, 0.f, 0.f, 0.f};
  acc[1] = f32x4{0.f, 0.f, 0.f, 0.f};

  auto stage = [&](int buf, int k0) {
    #pragma unroll
    for (int i = 0; i < 2; ++i) {
      int ii = w * 2 + i;
      GLD16(Ab + (size_t)((ii << 4) + srow) * 1024 + k0 + scol, &sA[buf][ii * 512]);
    }
    if (w == 0)
      GLD16(Bb + (size_t)srow * 1024 + k0 + scol, &sB[buf][0]);
  };

  stage(0, 0);
  int cur = 0;
  for (int t = 0; t < 32; ++t) {
    __syncthreads();
    if (t + 1 < 32) stage(cur ^ 1, (t + 1) << 5);
    bf16x8 bfv = *reinterpret_cast<const bf16x8*>(&sB[cur][lrow * 32 + kt]);
    #pragma unroll
    for (int mi = 0; mi < 2; ++mi) {
      bf16x8 af = *reinterpret_cast<const bf16x8*>(&sA[cur][((w * 2 + mi) * 16 + lrow) * 32 + kt]);
      acc[mi] = __builtin_amdgcn_mfma_f32_16x16x32_bf16(af, bfv, acc[mi], 0, 0, 0);
    }
    cur ^= 1;
  }

  const int rb = (lane >> 4) << 2;
  const int s = lrow;  // C col = lane&15
  #pragma unroll
  for (int mi = 0; mi < 2; ++mi) {
    int d0 = (dt << 7) + (w * 2 + mi) * 16 + rb;  // C rows (4 consecutive d)
    ushort4 o;
    o.x = f2bf(acc[mi][0]); o.y = f2bf(acc[mi][1]);
    o.z = f2bf(acc[mi][2]); o.w = f2bf(acc[mi][3]);
    *reinterpret_cast<ushort4*>(&A2[(size_t)((b << 4) + s) * 1024 + d0]) = o;
  }
}

// ---------------- MFMA GEMM 64x64 (slot-sized GEMMs + weight prep) ----------------

template<int BIAS, int RELU, int ADDSRC, int OUTBF16, int SCALE>
__global__ __launch_bounds__(256) void gemm_sm(
    const unsigned short* __restrict__ A, const unsigned short* __restrict__ W,
    const float* __restrict__ bias, const float* __restrict__ addsrc,
    void* __restrict__ Cout, int M, int N, int K, float scalev) {
  __shared__ unsigned short sA[2][2048];  // [64][32]
  __shared__ unsigned short sB[2][2048];
  const int tid = threadIdx.x;
  const int lane = tid & 63, w = tid >> 6;

  int nwg = gridDim.x * gridDim.y;
  int flat = blockIdx.y * gridDim.x + blockIdx.x;
  if ((nwg & 7) == 0) { int c = nwg >> 3; flat = (flat & 7) * c + (flat >> 3); }
  const int row0 = (flat / gridDim.x) << 6;
  const int col0 = (flat % gridDim.x) << 6;

  const int lrow = lane & 15, kt = (lane >> 4) << 3;
  const int srow = lane >> 2, scol = (lane & 3) << 3;

  f32x4 acc[4];
  #pragma unroll
  for (int m = 0; m < 4; ++m) acc[m] = f32x4{0.f, 0.f, 0.f, 0.f};

  auto stage = [&](int buf, int k0) {
    int r = (w << 4) + srow;
    GLD16(A + (size_t)(row0 + r) * K + k0 + scol, &sA[buf][w * 512]);
    GLD16(W + (size_t)(col0 + r) * K + k0 + scol, &sB[buf][w * 512]);
  };

  stage(0, 0);
  const int nt = K >> 5;
  int cur = 0;
  for (int t = 0; t < nt; ++t) {
    __syncthreads();
    if (t + 1 < nt) stage(cur ^ 1, (t + 1) << 5);
    bf16x8 af[4], bfv;
    #pragma unroll
    for (int m = 0; m < 4; ++m)
      af[m] = *reinterpret_cast<const bf16x8*>(&sA[cur][(m * 16 + lrow) * 32 + kt]);
    bfv = *reinterpret_cast<const bf16x8*>(&sB[cur][((w << 4) + lrow) * 32 + kt]);
    #pragma unroll
    for (int m = 0; m < 4; ++m)
      acc[m] = __builtin_amdgcn_mfma_f32_16x16x32_bf16(af[m], bfv, acc[m], 0, 0, 0);
    cur ^= 1;
  }

  const int rb = (lane >> 4) << 2;
  const int col = col0 + (w << 4) + lrow;
  float bv = BIAS ? bias[col] : 0.0f;
  #pragma unroll
  for (int m = 0; m < 4; ++m) {
    #pragma unroll
    for (int r = 0; r < 4; ++r) {
      int row = row0 + m * 16 + rb + r;
      float v = acc[m][r];
      if (SCALE) v *= scalev;
      v += bv;
      if (ADDSRC) v += addsrc[(size_t)row * N + col];
      if (RELU) v = fmaxf(v, 0.0f);
      if (OUTBF16) ((unsigned short*)Cout)[(size_t)row * N + col] = f2bf(v);
      else ((float*)Cout)[(size_t)row * N + col] = v;
    }
  }
}

// ---------------- host launch ----------------

extern "C" void kernel_launch(void* const* d_in, const int* in_sizes, int n_in,
                              void* d_out, int out_size, void* d_ws, size_t ws_size,
                              hipStream_t stream) {
  const float* inputs  = (const float*)d_in[0];
  const float* noise   = (const float*)d_in[1];
  const float* slot_mu = (const float*)d_in[2];
  const float* slot_ls = (const float*)d_in[3];
  const float* ln_in_g = (const float*)d_in[4];
  const float* ln_in_b = (const float*)d_in[5];
  const float* ln_s_g  = (const float*)d_in[6];
  const float* ln_s_b  = (const float*)d_in[7];
  const float* ln_m_g  = (const float*)d_in[8];
  const float* ln_m_b  = (const float*)d_in[9];
  const float* Wq   = (const float*)d_in[10];
  const float* Wk   = (const float*)d_in[11];
  const float* Wv   = (const float*)d_in[12];
  const float* w_ih = (const float*)d_in[13];
  const float* w_hh = (const float*)d_in[14];
  const float* b_ih = (const float*)d_in[15];
  const float* b_hh = (const float*)d_in[16];
  const float* w1   = (const float*)d_in[17];
  const float* b1   = (const float*)d_in[18];
  const float* w2   = (const float*)d_in[19];
  const float* b2   = (const float*)d_in[20];

  const int BN = 65536, BS = 1024;

  uintptr_t base = (uintptr_t)d_ws;
  auto alloc = [&](size_t bytes) {
    void* p = (void*)base;
    base += (bytes + 255) & ~(size_t)255;
    return p;
  };
  unsigned short* x_bf    = (unsigned short*)alloc((size_t)BN * 512 * 2);
  unsigned short* vT      = (unsigned short*)alloc((size_t)64 * 512 * 1024 * 2);
  unsigned short* wqT     = (unsigned short*)alloc(512 * 512 * 2);
  unsigned short* wkT     = (unsigned short*)alloc(512 * 512 * 2);
  unsigned short* wpt     = (unsigned short*)alloc(512 * 512 * 2);
  unsigned short* wv_bf   = (unsigned short*)alloc(512 * 512 * 2);
  unsigned short* wcat_bf = (unsigned short*)alloc((size_t)2048 * 1024 * 2);
  float*          bcat    = (float*)alloc(2048 * 4);
  unsigned short* w1_bf   = (unsigned short*)alloc(512 * 512 * 2);
  unsigned short* w2_bf   = (unsigned short*)alloc(512 * 512 * 2);
  float*          slots   = (float*)alloc((size_t)BS * 512 * 4);
  unsigned short* sn_bf   = (unsigned short*)alloc((size_t)BS * 512 * 2);
  unsigned short* A2      = (unsigned short*)alloc((size_t)BS * 1024 * 2);
  unsigned short* q2_bf   = (unsigned short*)alloc((size_t)BS * 512 * 2);
  float*          logits  = (float*)alloc((size_t)64 * 16 * 1024 * 4);
  unsigned short* attn_bf = (unsigned short*)alloc((size_t)64 * 16 * 1024 * 2);
  float*          gates   = (float*)alloc((size_t)BS * 2048 * 4);
  float*          sgru    = (float*)alloc((size_t)BS * 512 * 4);
  unsigned short* lnm_bf  = (unsigned short*)alloc((size_t)BS * 512 * 2);
  unsigned short* h_bf    = (unsigned short*)alloc((size_t)BS * 512 * 2);
  (void)ws_size; (void)n_in; (void)in_sizes; (void)out_size;

  const float scale = 0.044194173824159216f;  // 512^-0.5

  // weight prep: W'T[kp][e] = scale * sum_d WkT[kp,d] * WqT[e,d]  (MFMA)
  tcast_k<<<dim3(16, 16), 256, 0, stream>>>(Wq, wqT);
  tcast_k<<<dim3(16, 16), 256, 0, stream>>>(Wk, wkT);
  gemm_sm<0,0,0,1,1><<<dim3(8, 8), 256, 0, stream>>>(
      wkT, wqT, nullptr, nullptr, wpt, 512, 512, 512, scale);
  cast_bf16_k<<<1024, 256, 0, stream>>>(Wv, wv_bf, 262144);
  wcat_k<<<8192, 256, 0, stream>>>(w_ih, w_hh, wcat_bf);
  bcat_k<<<8, 256, 0, stream>>>(b_ih, b_hh, bcat);
  cast_bf16_k<<<1024, 256, 0, stream>>>(w1, w1_bf, 262144);
  cast_bf16_k<<<1024, 256, 0, stream>>>(w2, w2_bf, 262144);

  init_slots_k<<<2048, 256, 0, stream>>>(slot_mu, slot_ls, noise, slots);
  ln_rows_k<<<16384, 256, 0, stream>>>(inputs, ln_in_g, ln_in_b, x_bf, BN);
  gemm_vt<<<dim3(4, 512), 256, 0, stream>>>(x_bf, wv_bf, vT);

  for (int it = 0; it < 3; ++it) {
    ln_cast_k<<<256, 256, 0, stream>>>(slots, ln_s_g, ln_s_b, sn_bf, A2);
    q2_k<<<dim3(4, 64), 256, 0, stream>>>(sn_bf, wpt, q2_bf);
    logits_k<<<dim3(8, 64), 256, 0, stream>>>(q2_bf, x_bf, logits);
    softmax_cn_k<<<64, 1024, 0, stream>>>(logits, attn_bf);
    pv_k<<<dim3(4, 64), 256, 0, stream>>>(vT, attn_bf, A2);
    gemm_sm<1,0,0,0,0><<<dim3(32, 16), 256, 0, stream>>>(
        A2, wcat_bf, bcat, nullptr, gates, BS, 2048, 1024, 1.0f);
    gru_ln_k<<<256, 256, 0, stream>>>(gates, slots, ln_m_g, ln_m_b, sgru, lnm_bf);
    gemm_sm<1,1,0,1,0><<<dim3(8, 16), 256, 0, stream>>>(
        lnm_bf, w1_bf, b1, nullptr, h_bf, BS, 512, 512, 1.0f);
    float* slots_out = (it == 2) ? (float*)d_out : slots;
    gemm_sm<1,0,1,0,0><<<dim3(8, 16), 256, 0, stream>>>(
        h_bf, w2_bf, b2, sgru, slots_out, BS, 512, 512, 1.0f);
  }
}